// Round 1
// baseline (1724.858 us; speedup 1.0000x reference)
//
#include <hip/hip_runtime.h>
#include <hip/hip_bf16.h>
#include <math.h>

#define DEV __device__ __forceinline__

// ---------------------------------------------------------------------------
// Implicit-GEMM conv kernel. Tile: BM=128 pixels x BN ocs, BK=16, 256 threads.
// Thread (ti=t&15, tj=t>>4) owns pixels {ti*4+i, 64+ti*4+i} and ocs
// {tj*4+j (+64 if BN=128)} -> 2-way LDS bank aliasing only (free).
// ---------------------------------------------------------------------------

enum { M_CONV1, M_CONV2, M_PREVQ, M_POSTVQ, M_DECONV1 };

template<int MODE> struct Cfg;
template<> struct Cfg<M_CONV1>  { static constexpr int K=48,   BN=128, NOC=128, RELU=1; };
template<> struct Cfg<M_CONV2>  { static constexpr int K=2048, BN=128, NOC=256, RELU=1; };
template<> struct Cfg<M_PREVQ>  { static constexpr int K=256,  BN=64,  NOC=64,  RELU=0; };
template<> struct Cfg<M_POSTVQ> { static constexpr int K=576,  BN=128, NOC=256, RELU=0; };
template<> struct Cfg<M_DECONV1>{ static constexpr int K=1024, BN=128, NOC=128, RELU=1; };

template<int MODE>
DEV float gatherA(const float* __restrict__ src, int n, int h, int w, int k,
                  int py, int px) {
  if constexpr (MODE == M_CONV1) {
    int ic = k >> 4, r = k & 15;
    int ih = 2*h - 1 + (r >> 2), iw = 2*w - 1 + (r & 3);
    return ((unsigned)ih < 256u && (unsigned)iw < 256u)
      ? src[((n*3 + ic) << 16) + (ih << 8) + iw] : 0.f;
  } else if constexpr (MODE == M_CONV2) {
    int ic = k >> 4, r = k & 15;
    int ih = 2*h - 1 + (r >> 2), iw = 2*w - 1 + (r & 3);
    return ((unsigned)ih < 128u && (unsigned)iw < 128u)
      ? src[((n*128 + ic) << 14) + (ih << 7) + iw] : 0.f;
  } else if constexpr (MODE == M_PREVQ) {
    return src[((n*256 + k) << 12) + (h << 6) + w];
  } else if constexpr (MODE == M_POSTVQ) {
    int ic = k & 63, r = k >> 6;          // k = r*64 + ic, r = kh*3+kw
    int kh = r / 3, kw = r - 3*kh;
    int ih = h - 1 + kh, iw = w - 1 + kw;
    return ((unsigned)ih < 64u && (unsigned)iw < 64u)
      ? src[((n*64 + ic) << 12) + (ih << 6) + iw] : 0.f;
  } else {                                 // M_DECONV1: h,w are parity-subgrid coords
    int ic = k >> 2, j1 = (k >> 1) & 1, j0 = k & 1;
    int ih = h + py - 1 + j1, iw = w + px - 1 + j0;
    return ((unsigned)ih < 64u && (unsigned)iw < 64u)
      ? src[((n*256 + ic) << 12) + (ih << 6) + iw] : 0.f;
  }
}

template<int MODE>
__global__ __launch_bounds__(256, 2) void conv_gemm(const float* __restrict__ src,
                                                    const float* __restrict__ Bt,
                                                    const float* __restrict__ bias,
                                                    float* __restrict__ out) {
  constexpr int K   = Cfg<MODE>::K;
  constexpr int BN  = Cfg<MODE>::BN;
  constexpr int NOC = Cfg<MODE>::NOC;
  constexpr int NTILES = NOC / BN;
  constexpr int NH = BN / 64;            // oc halves (1 or 2)

  __shared__ __align__(16) float As[16*128];
  __shared__ __align__(16) float Bs[16*BN];

  int t = threadIdx.x;
  int nt = (NTILES > 1) ? (int)(blockIdx.x % NTILES) : 0;
  int mt = (NTILES > 1) ? (int)(blockIdx.x / NTILES) : (int)blockIdx.x;
  int py = 0, px = 0;
  if constexpr (MODE == M_DECONV1) {
    int par = blockIdx.y; py = par >> 1; px = par & 1;
    Bt += (size_t)par * (K * NOC);
  }

  // A-loader coords (fixed per thread)
  int pl = t & 127, kb = t >> 7;
  int p = mt * 128 + pl;
  int n, h, w;
  if constexpr (MODE == M_CONV1) { n = p >> 14; h = (p >> 7) & 127; w = p & 127; }
  else                           { n = p >> 12; h = (p >> 6) & 63;  w = p & 63;  }

  int ti = t & 15, tj = t >> 4;

  float acc[8][NH*4];
  #pragma unroll
  for (int i = 0; i < 8; ++i)
    #pragma unroll
    for (int j = 0; j < NH*4; ++j) acc[i][j] = 0.f;

  for (int k0 = 0; k0 < K; k0 += 16) {
    // A: 8 gathered elems per thread -> As[k][pix]
    #pragma unroll
    for (int jj = 0; jj < 8; ++jj) {
      int kr = jj*2 + kb;
      As[kr*128 + pl] = gatherA<MODE>(src, n, h, w, k0 + kr, py, px);
    }
    // B: coalesced float4 copies -> Bs[k][oc]
    #pragma unroll
    for (int jj = 0; jj < (16*BN/4)/256; ++jj) {
      int id = jj*256 + t;
      int kr = id / (BN/4), c4 = id % (BN/4);
      ((float4*)Bs)[kr*(BN/4) + c4] =
          *((const float4*)(Bt + (size_t)(k0 + kr)*NOC + nt*BN) + c4);
    }
    __syncthreads();
    #pragma unroll
    for (int kk = 0; kk < 16; ++kk) {
      float4 a0 = *(const float4*)&As[kk*128 + ti*4];
      float4 a1 = *(const float4*)&As[kk*128 + ti*4 + 64];
      float4 b0 = *(const float4*)&Bs[kk*BN + tj*4];
      float a[8] = {a0.x,a0.y,a0.z,a0.w,a1.x,a1.y,a1.z,a1.w};
      float b[NH*4];
      b[0]=b0.x; b[1]=b0.y; b[2]=b0.z; b[3]=b0.w;
      if constexpr (NH == 2) {
        float4 b1 = *(const float4*)&Bs[kk*BN + tj*4 + 64];
        b[4]=b1.x; b[5]=b1.y; b[6]=b1.z; b[7]=b1.w;
      }
      #pragma unroll
      for (int i = 0; i < 8; ++i)
        #pragma unroll
        for (int j = 0; j < NH*4; ++j)
          acc[i][j] += a[i]*b[j];
    }
    __syncthreads();
  }

  // epilogue
  #pragma unroll
  for (int i = 0; i < 8; ++i) {
    int pp = mt*128 + (i>>2)*64 + ti*4 + (i&3);
    int nn, hh, ww;
    if constexpr (MODE == M_CONV1) { nn = pp >> 14; hh = (pp >> 7) & 127; ww = pp & 127; }
    else                           { nn = pp >> 12; hh = (pp >> 6) & 63;  ww = pp & 63;  }
    #pragma unroll
    for (int j = 0; j < NH*4; ++j) {
      int oc = nt*BN + (j>>2)*64 + tj*4 + (j&3);
      float v = acc[i][j] + bias[oc];
      if constexpr (Cfg<MODE>::RELU) v = fmaxf(v, 0.f);
      if constexpr (MODE == M_CONV1)
        out[((nn*128 + oc) << 14) + (hh << 7) + ww] = v;
      else if constexpr (MODE == M_CONV2)
        out[((nn*256 + oc) << 12) + (hh << 6) + ww] = v;
      else if constexpr (MODE == M_PREVQ)
        out[((nn*64 + oc) << 12) + (hh << 6) + ww] = v;
      else if constexpr (MODE == M_POSTVQ)
        out[((nn*256 + oc) << 12) + (hh << 6) + ww] = v;
      else { // DECONV1
        int oh = 2*hh + py, ow2 = 2*ww + px;
        out[((nn*128 + oc) << 14) + (oh << 7) + ow2] = v;
      }
    }
  }
}

// ---------------------------------------------------------------------------
// Weight pre-transposes into [k][oc] layouts (coalesced B loads).
// ---------------------------------------------------------------------------
__global__ void prep_bt1(const float* __restrict__ ew1, float* __restrict__ bt) {
  int i = blockIdx.x*256 + threadIdx.x; if (i >= 48*128) return;
  int k = i >> 7, oc = i & 127;
  bt[i] = ew1[oc*48 + k];
}
__global__ void prep_bt2(const float* __restrict__ ew2, float* __restrict__ bt) {
  int i = blockIdx.x*256 + threadIdx.x; if (i >= 2048*256) return;
  int k = i >> 8, oc = i & 255;
  bt[i] = ew2[oc*2048 + k];
}
__global__ void prep_btp(const float* __restrict__ pvw, float* __restrict__ bt) {
  int i = blockIdx.x*256 + threadIdx.x; if (i >= 256*64) return;
  int k = i >> 6, oc = i & 63;
  bt[i] = pvw[oc*256 + k];
}
__global__ void prep_btq(const float* __restrict__ qvw, float* __restrict__ bt) {
  int i = blockIdx.x*256 + threadIdx.x; if (i >= 576*256) return;
  int k = i >> 8, oc = i & 255;
  int r = k >> 6, ic = k & 63;                 // k = r*64+ic
  bt[i] = qvw[oc*576 + ic*9 + r];
}
__global__ void prep_btd(const float* __restrict__ dw1, float* __restrict__ bt) {
  int i = blockIdx.x*256 + threadIdx.x; if (i >= 4*1024*128) return;
  int oc = i & 127, k = (i >> 7) & 1023, par = i >> 17;
  int py = par >> 1, px = par & 1;
  int ic = k >> 2, j1 = (k >> 1) & 1, j0 = k & 1;
  bt[i] = dw1[((oc*256 + ic) << 4) + (py + 2*j1)*4 + (px + 2*j0)];
}

// ---------------------------------------------------------------------------
// Vector quantization: 1 pixel per thread, codebook in 32KB LDS chunks.
// dist = ||e||^2 - 2 x.e (same argmin as reference); first-index tie-break.
// ---------------------------------------------------------------------------
__global__ __launch_bounds__(256, 2) void vq_kernel(const float* __restrict__ ze,
                                                    const float* __restrict__ emb,
                                                    float* __restrict__ quant,
                                                    int* __restrict__ hist,
                                                    float* __restrict__ loss_sum) {
  __shared__ __align__(16) float E[128*64];
  __shared__ float nrm[128];
  int t = threadIdx.x;
  int p = blockIdx.x*256 + t;
  int n = p >> 12, sp = p & 4095;
  const float* zb = ze + ((size_t)n << 18) + sp;
  float x[64];
  #pragma unroll
  for (int d = 0; d < 64; ++d) x[d] = zb[(size_t)d << 12];

  float best = 3.402823466e38f; int bi = 0;
  for (int c = 0; c < 4; ++c) {
    __syncthreads();
    const float4* src4 = (const float4*)(emb + c*128*64);
    #pragma unroll
    for (int i = 0; i < 8; ++i) ((float4*)E)[t + i*256] = src4[t + i*256];
    __syncthreads();
    if (t < 128) {
      float s = 0.f;
      const float4* row = (const float4*)&E[t << 6];
      #pragma unroll
      for (int i = 0; i < 16; ++i) {
        float4 v = row[i]; s += v.x*v.x + v.y*v.y + v.z*v.z + v.w*v.w;
      }
      nrm[t] = s;
    }
    __syncthreads();
    for (int k = 0; k < 128; ++k) {
      const float4* row = (const float4*)&E[k << 6];
      float dot = 0.f;
      #pragma unroll
      for (int i = 0; i < 16; ++i) {
        float4 v = row[i];
        dot += v.x*x[4*i] + v.y*x[4*i+1] + v.z*x[4*i+2] + v.w*x[4*i+3];
      }
      float dist = nrm[k] - 2.f*dot;
      if (dist < best) { best = dist; bi = c*128 + k; }
    }
  }

  atomicAdd(&hist[bi], 1);
  float ls = 0.f;
  const float* er = emb + (bi << 6);
  float* qb = quant + ((size_t)n << 18) + sp;
  #pragma unroll
  for (int d = 0; d < 64; ++d) {
    float e = er[d];
    qb[(size_t)d << 12] = e;
    float df = e - x[d]; ls += df*df;
  }
  #pragma unroll
  for (int o = 32; o; o >>= 1) ls += __shfl_down(ls, o, 64);
  if ((t & 63) == 0) atomicAdd(loss_sum, ls);
}

__global__ void finalize_kernel(const int* __restrict__ hist,
                                const float* __restrict__ loss_sum,
                                float* __restrict__ out_loss,
                                float* __restrict__ out_perp) {
  __shared__ float red[512];
  int t = threadIdx.x;
  float c = (float)hist[t];
  float pr = c * (1.f/32768.f);
  red[t] = pr * logf(pr + 1e-10f);
  __syncthreads();
  for (int s = 256; s; s >>= 1) {
    if (t < s) red[t] += red[t + s];
    __syncthreads();
  }
  if (t == 0) {
    out_loss[0] = 1.25f * loss_sum[0] * (1.f/2097152.f);  // (1+0.25)*MSE
    out_perp[0] = expf(-red[0]);
  }
}

// ---------------------------------------------------------------------------
// Final transposed conv 128->3 (k=4,s=2,p=1), direct per-pixel, weights in LDS.
// ---------------------------------------------------------------------------
__global__ __launch_bounds__(256) void deconv2_kernel(const float* __restrict__ g2,
                                                      const float* __restrict__ dw2,
                                                      const float* __restrict__ db2,
                                                      float* __restrict__ out) {
  __shared__ __align__(16) float W[6144]; // [3][128][4][4]
  int t = threadIdx.x;
  #pragma unroll
  for (int i = 0; i < 6; ++i)
    ((float4*)W)[t + i*256] = ((const float4*)dw2)[t + i*256];
  __syncthreads();
  int p = blockIdx.x*256 + t;
  int n = p >> 16, oh = (p >> 8) & 255, ow = p & 255;
  int py = oh & 1, px = ow & 1;
  int ihb = ((oh + 1) >> 1) - 1, iwb = ((ow + 1) >> 1) - 1;
  float a0 = db2[0], a1 = db2[1], a2 = db2[2];
  const float* gb = g2 + ((size_t)n << 21);
  #pragma unroll
  for (int j1 = 0; j1 < 2; ++j1)
    #pragma unroll
    for (int j0 = 0; j0 < 2; ++j0) {
      int ih = ihb + j1, iw = iwb + j0;
      if ((unsigned)ih < 128u && (unsigned)iw < 128u) {
        int kidx = (py + 2*j1)*4 + (px + 2*j0);
        const float* gp = gb + (ih << 7) + iw;
        const float* wp = W + kidx;
        #pragma unroll 4
        for (int ic = 0; ic < 128; ++ic) {
          float xv = gp[(size_t)ic << 14];
          a0 += xv * wp[ic*16];
          a1 += xv * wp[2048 + ic*16];
          a2 += xv * wp[4096 + ic*16];
        }
      }
    }
  out[( (n*3    ) << 16) + (oh << 8) + ow] = a0;
  out[( (n*3 + 1) << 16) + (oh << 8) + ow] = a1;
  out[( (n*3 + 2) << 16) + (oh << 8) + ow] = a2;
}

// ---------------------------------------------------------------------------
extern "C" void kernel_launch(void* const* d_in, const int* in_sizes, int n_in,
                              void* d_out, int out_size, void* d_ws, size_t ws_size,
                              hipStream_t stream) {
  (void)in_sizes; (void)n_in; (void)ws_size;
  const float* x   = (const float*)d_in[0];
  const float* ew1 = (const float*)d_in[1];
  const float* eb1 = (const float*)d_in[2];
  const float* ew2 = (const float*)d_in[3];
  const float* eb2 = (const float*)d_in[4];
  const float* pvw = (const float*)d_in[5];
  const float* pvb = (const float*)d_in[6];
  const float* emb = (const float*)d_in[7];
  const float* qvw = (const float*)d_in[8];
  const float* qvb = (const float*)d_in[9];
  const float* dw1 = (const float*)d_in[10];
  const float* db1 = (const float*)d_in[11];
  const float* dw2 = (const float*)d_in[12];
  const float* db2 = (const float*)d_in[13];
  float* out = (float*)d_out;

  char* ws = (char*)d_ws;
  float* h1   = (float*)(ws);                     // 16777216 f (67.1MB); later g2
  float* h2   = (float*)(ws + 67108864);          //  8388608 f (33.5MB); later g
  float* ze   = (float*)(ws + 100663296);         //  2097152 f
  float* qz   = (float*)(ws + 109051904);         //  2097152 f
  int*   hist = (int*)  (ws + 117440512);         //  512 ints
  float* loss_sum = (float*)(ws + 117440512 + 2048);
  float* bt1 = (float*)(ws + 117444608);
  float* bt2 = bt1 + 48*128;
  float* btp = bt2 + 2048*256;
  float* btq = btp + 256*64;
  float* btd = btq + 576*256;
  float* g  = h2;   // reuse (h2 dead after prevq)
  float* g2 = h1;   // reuse (h1 dead after conv2)

  hipMemsetAsync(hist, 0, 2048 + 64, stream);

  prep_bt1<<<24,   256, 0, stream>>>(ew1, bt1);
  prep_bt2<<<2048, 256, 0, stream>>>(ew2, bt2);
  prep_btp<<<64,   256, 0, stream>>>(pvw, btp);
  prep_btq<<<576,  256, 0, stream>>>(qvw, btq);
  prep_btd<<<2048, 256, 0, stream>>>(dw1, btd);

  conv_gemm<M_CONV1><<<1024, 256, 0, stream>>>(x,  bt1, eb1, h1);
  conv_gemm<M_CONV2><<<512,  256, 0, stream>>>(h1, bt2, eb2, h2);
  conv_gemm<M_PREVQ><<<256,  256, 0, stream>>>(h2, btp, pvb, ze);

  vq_kernel<<<128, 256, 0, stream>>>(ze, emb, qz, hist, loss_sum);
  finalize_kernel<<<1, 512, 0, stream>>>(hist, loss_sum, out, out + (out_size - 1));

  conv_gemm<M_POSTVQ> <<<512, 256, 0, stream>>>(qz, btq, qvb, g);
  conv_gemm<M_DECONV1><<<dim3(256,4), 256, 0, stream>>>(g, btd, db1, g2);
  deconv2_kernel<<<2048, 256, 0, stream>>>(g2, dw2, db2, out + 1);
}

// Round 3
// 1191.791 us; speedup vs baseline: 1.4473x; 1.4473x over previous
//
#include <hip/hip_runtime.h>
#include <math.h>

typedef unsigned short u16;
typedef unsigned int uint;
typedef __attribute__((ext_vector_type(8))) short bh8;   // 8 bf16 in 4 VGPRs
typedef __attribute__((ext_vector_type(4))) float f32x4;

#define DEV __device__ __forceinline__

DEV u16 f2bf(float x) {                       // fp32 -> bf16 RNE
  uint u = __builtin_bit_cast(uint, x);
  return (u16)((u + 0x7FFFu + ((u >> 16) & 1u)) >> 16);
}

union Pack { u16 u[8]; uint4 v; };

DEV uint2 pack4(float v0, float v1, float v2, float v3) {
  uint2 s;
  s.x = (uint)f2bf(v0) | ((uint)f2bf(v1) << 16);
  s.y = (uint)f2bf(v2) | ((uint)f2bf(v3) << 16);
  return s;
}

// ===========================================================================
// ENCODER: fp32 VALU implicit-GEMM (exact numerics for the VQ argmin).
// BM pixels x BN ocs, BK=16, 256 threads, per-thread (MH*4)x(NH*4) outputs.
// ===========================================================================
enum { F_CONV1, F_CONV2, F_PREVQ };

template<int MODE> struct FCfg;
template<> struct FCfg<F_CONV1> { static constexpr int K=48,   BM=128, BN=128, NOC=128, RELU=1; };
template<> struct FCfg<F_CONV2> { static constexpr int K=2048, BM=128, BN=64,  NOC=256, RELU=1; };
template<> struct FCfg<F_PREVQ> { static constexpr int K=256,  BM=64,  BN=64,  NOC=64,  RELU=0; };

template<int MODE>
DEV float gatherF(const float* __restrict__ src, int n, int h, int w, int k) {
  if constexpr (MODE == F_CONV1) {            // k = ic*16 + r
    int ic = k >> 4, r = k & 15;
    int ih = 2*h - 1 + (r >> 2), iw = 2*w - 1 + (r & 3);
    return ((unsigned)ih < 256u && (unsigned)iw < 256u)
      ? src[((n*3 + ic) << 16) + (ih << 8) + iw] : 0.f;
  } else if constexpr (MODE == F_CONV2) {     // k = r*128 + ic (tap-major)
    int r = k >> 7, ic = k & 127;
    int ih = 2*h - 1 + (r >> 2), iw = 2*w - 1 + (r & 3);
    return ((unsigned)ih < 128u && (unsigned)iw < 128u)
      ? src[((n*128 + ic) << 14) + (ih << 7) + iw] : 0.f;
  } else {                                    // PREVQ: k = ic
    return src[((n*256 + k) << 12) + (h << 6) + w];
  }
}

template<int MODE>
__global__ __launch_bounds__(256, 4) void conv_f32(const float* __restrict__ src,
                                                   const float* __restrict__ Bt,
                                                   const float* __restrict__ bias,
                                                   float* __restrict__ out) {
  constexpr int K  = FCfg<MODE>::K,  BM = FCfg<MODE>::BM;
  constexpr int BN = FCfg<MODE>::BN, NOC = FCfg<MODE>::NOC;
  constexpr int NT = NOC / BN;
  constexpr int MH = BM / 64, NH = BN / 64;
  constexpr int AE = 16*BM/256, KS = 256/BM;   // A elems/thread, k-row stride

  __shared__ __align__(16) float As[16*BM];
  __shared__ __align__(16) float Bs[16*BN];

  const int t = threadIdx.x;
  const int nt = (NT > 1) ? (int)(blockIdx.x % NT) : 0;
  const int mt = (NT > 1) ? (int)(blockIdx.x / NT) : (int)blockIdx.x;

  const int pl = t & (BM-1), kb = t / BM;
  const int p = mt*BM + pl;
  int n, h, w;
  if constexpr (MODE == F_CONV1) { n = p >> 14; h = (p >> 7) & 127; w = p & 127; }
  else                           { n = p >> 12; h = (p >> 6) & 63;  w = p & 63;  }

  const int ti = t & 15, tj = t >> 4;

  float acc[MH*4][NH*4];
  #pragma unroll
  for (int i = 0; i < MH*4; ++i)
    #pragma unroll
    for (int j = 0; j < NH*4; ++j) acc[i][j] = 0.f;

  for (int k0 = 0; k0 < K; k0 += 16) {
    #pragma unroll
    for (int jj = 0; jj < AE; ++jj) {
      int kr = jj*KS + kb;
      As[kr*BM + pl] = gatherF<MODE>(src, n, h, w, k0 + kr);
    }
    #pragma unroll
    for (int jj = 0; jj < (16*BN/4)/256; ++jj) {
      int id = jj*256 + t;
      int kr = id / (BN/4), c4 = id % (BN/4);
      ((float4*)Bs)[kr*(BN/4) + c4] =
          *((const float4*)(Bt + (size_t)(k0 + kr)*NOC + nt*BN) + c4);
    }
    __syncthreads();
    #pragma unroll
    for (int kk = 0; kk < 16; ++kk) {
      float a[MH*4], b[NH*4];
      *(float4*)&a[0] = *(const float4*)&As[kk*BM + ti*4];
      if constexpr (MH == 2) *(float4*)&a[4] = *(const float4*)&As[kk*BM + 64 + ti*4];
      *(float4*)&b[0] = *(const float4*)&Bs[kk*BN + tj*4];
      if constexpr (NH == 2) *(float4*)&b[4] = *(const float4*)&Bs[kk*BN + 64 + tj*4];
      #pragma unroll
      for (int i = 0; i < MH*4; ++i)
        #pragma unroll
        for (int j = 0; j < NH*4; ++j)
          acc[i][j] += a[i]*b[j];
    }
    __syncthreads();
  }

  #pragma unroll
  for (int i = 0; i < MH*4; ++i) {
    int pp = mt*BM + (i>>2)*64 + ti*4 + (i&3);
    int nn, hh, ww;
    if constexpr (MODE == F_CONV1) { nn = pp >> 14; hh = (pp >> 7) & 127; ww = pp & 127; }
    else                           { nn = pp >> 12; hh = (pp >> 6) & 63;  ww = pp & 63;  }
    #pragma unroll
    for (int j = 0; j < NH*4; ++j) {
      int oc = nt*BN + (j>>2)*64 + tj*4 + (j&3);
      float v = acc[i][j] + bias[oc];
      if constexpr (FCfg<MODE>::RELU) v = fmaxf(v, 0.f);
      if constexpr (MODE == F_CONV1)
        out[((nn*128 + oc) << 14) + (hh << 7) + ww] = v;
      else if constexpr (MODE == F_CONV2)
        out[((nn*256 + oc) << 12) + (hh << 6) + ww] = v;
      else
        out[((nn*64 + oc) << 12) + (hh << 6) + ww] = v;
    }
  }
}

// ===========================================================================
// DECODER: bf16 MFMA implicit-GEMM (verified round-2). BM=128, BK=64.
// ===========================================================================
enum { M_POSTVQ, M_DECONV1, M_DECONV2 };

template<int MODE> struct Cfg;
template<> struct Cfg<M_POSTVQ> { static constexpr int K=576,  BN=128, NOC=256, RELU=0; };
template<> struct Cfg<M_DECONV1>{ static constexpr int K=1024, BN=128, NOC=128, RELU=1; };
template<> struct Cfg<M_DECONV2>{ static constexpr int K=512,  BN=16,  NOC=16,  RELU=0; };

template<int MODE>
__global__ __launch_bounds__(256, 2) void conv_mfma(const void* __restrict__ src_,
                                                    const u16* __restrict__ Bt,
                                                    const float* __restrict__ bias,
                                                    void* __restrict__ out_) {
  constexpr int K  = Cfg<MODE>::K;
  constexpr int BN = Cfg<MODE>::BN;
  constexpr int NOC = Cfg<MODE>::NOC;
  constexpr int NT = NOC / BN;
  constexpr int WM = (BN == 128) ? 2 : 4;
  constexpr int WN = (BN == 128) ? 2 : 1;
  constexpr int FM = 128 / WM / 16;
  constexpr int FN = BN / WN / 16;

  __shared__ u16 As[128 * 72];
  __shared__ u16 Bs[BN * 72];

  const int t = threadIdx.x;
  const int nt = (NT > 1) ? (int)(blockIdx.x % NT) : 0;
  const int mt = (NT > 1) ? (int)(blockIdx.x / NT) : (int)blockIdx.x;
  int par = 0;
  if constexpr (MODE == M_DECONV1 || MODE == M_DECONV2) {
    par = blockIdx.y;
    Bt += (size_t)par * NOC * K;
  }

  const int pl = t & 127, kb = t >> 7;
  const int p = mt * 128 + pl;
  int n, h, w;
  if constexpr (MODE == M_DECONV2) { n = p >> 14; h = (p >> 7) & 127; w = p & 127; }
  else                             { n = p >> 12; h = (p >> 6) & 63;  w = p & 63;  }

  const int lane = t & 63, wv = t >> 6;
  const int lr = lane & 15, lg = lane >> 4;
  const int wm = (WM == 2) ? (wv & 1) : wv;
  const int wn = (WM == 2) ? (wv >> 1) : 0;

  f32x4 acc[FM][FN];
  #pragma unroll
  for (int fm = 0; fm < FM; ++fm)
    #pragma unroll
    for (int fn = 0; fn < FN; ++fn)
      #pragma unroll
      for (int q = 0; q < 4; ++q) acc[fm][fn][q] = 0.f;

  const u16* srcu = (const u16*)src_;

  for (int k0 = 0; k0 < K; k0 += 64) {
    __syncthreads();
    Pack pk[4];
    if constexpr (MODE == M_DECONV2) {
      int tap = k0 >> 7, icb = k0 & 127;
      int j1 = tap >> 1, j0 = tap & 1;
      int qy = par >> 1, qx = par & 1;
      int ih = h - 1 + qy + j1, iw = w - 1 + qx + j0;
      bool ok = ((unsigned)ih < 128u) && ((unsigned)iw < 128u);
      int ipar = ((ih & 1) << 1) | (iw & 1);
      const u16* sb = srcu + ((((size_t)(n*4 + ipar)) << 12) + ((ih >> 1) << 6) + (iw >> 1)) * 128
                          + icb + kb * 32;
      #pragma unroll
      for (int i = 0; i < 4; ++i)
        pk[i].v = ok ? *(const uint4*)(sb + i*8) : make_uint4(0,0,0,0);
    } else {
      const u16* sb; bool ok = true;
      if constexpr (MODE == M_POSTVQ) {
        int r = k0 >> 6, kh = r / 3, kw = r - 3*kh;
        int ih = h - 1 + kh, iw = w - 1 + kw;
        ok = ((unsigned)ih < 64u) && ((unsigned)iw < 64u);
        sb = srcu + (size_t)(((n << 6) + kb*32) << 12) + (ih << 6) + iw;
      } else { // M_DECONV1
        int j = k0 >> 8, icb = k0 & 255;
        int j1 = j >> 1, j0 = j & 1;
        int py = par >> 1, px = par & 1;
        int ih = h + py - 1 + j1, iw = w + px - 1 + j0;
        ok = ((unsigned)ih < 64u) && ((unsigned)iw < 64u);
        sb = srcu + (size_t)((n*256 + icb + kb*32) << 12) + (ih << 6) + iw;
      }
      #pragma unroll
      for (int jj = 0; jj < 32; ++jj) {
        u16 v = ok ? sb[(size_t)jj * 4096] : (u16)0;
        pk[jj >> 3].u[jj & 7] = v;
      }
    }
    #pragma unroll
    for (int i = 0; i < 4; ++i)
      *(uint4*)&As[pl*72 + kb*32 + i*8] = pk[i].v;

    constexpr int NBI = (BN*8 + 255) / 256;
    #pragma unroll
    for (int i = 0; i < NBI; ++i) {
      int id = i*256 + t;
      bool okb = true;
      if constexpr ((BN*8) % 256 != 0) okb = (id < BN*8);
      if (okb) {
        int oc = id >> 3, ch = id & 7;
        *(uint4*)&Bs[oc*72 + ch*8] = *(const uint4*)(Bt + (size_t)oc*K + k0 + ch*8);
      }
    }
    __syncthreads();

    #pragma unroll
    for (int ks = 0; ks < 2; ++ks) {
      bh8 af[FM];
      #pragma unroll
      for (int fm = 0; fm < FM; ++fm)
        af[fm] = *(const bh8*)&As[(wm*(128/WM) + fm*16 + lr)*72 + ks*32 + lg*8];
      #pragma unroll
      for (int fn = 0; fn < FN; ++fn) {
        bh8 bf = *(const bh8*)&Bs[(wn*(BN/WN) + fn*16 + lr)*72 + ks*32 + lg*8];
        #pragma unroll
        for (int fm = 0; fm < FM; ++fm)
          acc[fm][fn] = __builtin_amdgcn_mfma_f32_16x16x32_bf16(af[fm], bf, acc[fm][fn], 0, 0, 0);
      }
    }
  }

  u16*   outu = (u16*)out_;
  float* outf = (float*)out_;
  #pragma unroll
  for (int fm = 0; fm < FM; ++fm) {
    const int pq = mt*128 + wm*(128/WM) + fm*16 + lg*4;
    int nn, hwq;
    if constexpr (MODE == M_DECONV2) { nn = pq >> 14; hwq = pq & 16383; }
    else                             { nn = pq >> 12; hwq = pq & 4095;  }
    #pragma unroll
    for (int fn = 0; fn < FN; ++fn) {
      const int oc = nt*BN + wn*(BN/WN) + fn*16 + lr;
      float bvv;
      if constexpr (MODE == M_DECONV2) bvv = (lr < 3) ? bias[oc] : 0.f;
      else                             bvv = bias[oc];
      float v0 = acc[fm][fn][0] + bvv, v1 = acc[fm][fn][1] + bvv;
      float v2 = acc[fm][fn][2] + bvv, v3 = acc[fm][fn][3] + bvv;
      if constexpr (Cfg<MODE>::RELU) {
        v0 = fmaxf(v0, 0.f); v1 = fmaxf(v1, 0.f); v2 = fmaxf(v2, 0.f); v3 = fmaxf(v3, 0.f);
      }
      if constexpr (MODE == M_POSTVQ) {
        *(uint2*)(outu + (((size_t)(nn*256 + oc)) << 12) + hwq) = pack4(v0,v1,v2,v3);
      } else if constexpr (MODE == M_DECONV1) {
        u16* ob = outu + (((size_t)(nn*4 + par)) << 19) + (size_t)hwq * 128 + oc;
        ob[0]   = f2bf(v0);
        ob[128] = f2bf(v1);
        ob[256] = f2bf(v2);
        ob[384] = f2bf(v3);
      } else { // M_DECONV2 -> x_recon fp32
        if (lr < 3) {
          const int hq = (pq >> 7) & 127, wq = pq & 127;
          const int qy = par >> 1, qx = par & 1;
          const int oh = 2*hq + qy;
          float* ob = outf + (((size_t)(nn*3 + oc)) << 16) + (oh << 8) + qx;
          ob[2*wq]     = v0;
          ob[2*wq + 2] = v1;
          ob[2*wq + 4] = v2;
          ob[2*wq + 6] = v3;
        }
      }
    }
  }
}

// ===========================================================================
// Weight preps
// ===========================================================================
__global__ void prep_enc(const float* __restrict__ ew1, const float* __restrict__ ew2,
                         const float* __restrict__ pvw,
                         float* bt1, float* bt2, float* btp) {
  int i = blockIdx.x * 256 + threadIdx.x;
  if (i < 6144) {                               // bt1 [k=ic*16+r][128]
    int k = i >> 7, oc = i & 127;
    bt1[i] = ew1[oc*48 + k];
  } else if ((i -= 6144) < 524288) {            // bt2 [k=r*128+ic][256]
    int k = i >> 8, oc = i & 255;
    int r = k >> 7, ic = k & 127;
    bt2[i] = ew2[oc*2048 + ic*16 + r];
  } else if ((i -= 524288) < 16384) {           // btp [k][64]
    int k = i >> 6, oc = i & 63;
    btp[i] = pvw[oc*256 + k];
  }
}

__global__ void prep_dec(const float* __restrict__ qvw, const float* __restrict__ dw1,
                         const float* __restrict__ dw2,
                         u16* btq, u16* btd, u16* btd2) {
  int i = blockIdx.x * 256 + threadIdx.x;
  if (i < 147456) {                             // btq [oc][k=r*64+ic]
    int oc = i / 576, rem = i - oc*576, r = rem >> 6, ic = rem & 63;
    btq[i] = f2bf(qvw[oc*576 + ic*9 + r]);
  } else if ((i -= 147456) < 524288) {          // btd [par][oc][k=j*256+ic]
    int pr = i >> 17, oc = (i >> 10) & 127, j = (i >> 8) & 3, ic = i & 255;
    int py = pr >> 1, px = pr & 1, j1 = j >> 1, j0 = j & 1;
    btd[i] = f2bf(dw1[oc*4096 + ic*16 + (py + 2*j1)*4 + (px + 2*j0)]);
  } else if ((i -= 524288) < 32768) {           // btd2 [q][oc16][k=tap*128+ic]
    int q = i >> 13, oc = (i >> 9) & 15, tap = (i >> 7) & 3, ic = i & 127;
    int qy = q >> 1, qx = q & 1, j1 = tap >> 1, j0 = tap & 1;
    btd2[i] = (oc < 3) ? f2bf(dw2[oc*2048 + ic*16 + (qy + 2*j1)*4 + (qx + 2*j0)]) : (u16)0;
  }
}

// ===========================================================================
// VQ: fp32-exact argmin + quantize (+ bf16 qz for decoder) + loss/hist
// ===========================================================================
__global__ __launch_bounds__(256, 2) void vq_kernel(const float* __restrict__ ze,
                                                    const float* __restrict__ emb,
                                                    u16* __restrict__ quant,
                                                    int* __restrict__ hist,
                                                    float* __restrict__ loss_sum) {
  __shared__ __align__(16) float E[128*64];
  __shared__ float nrm[128];
  int t = threadIdx.x;
  int p = blockIdx.x*256 + t;
  int n = p >> 12, sp = p & 4095;
  const float* zb = ze + ((size_t)n << 18) + sp;
  float x[64];
  #pragma unroll
  for (int d = 0; d < 64; ++d) x[d] = zb[(size_t)d << 12];

  float best = 3.402823466e38f; int bi = 0;
  for (int c = 0; c < 4; ++c) {
    __syncthreads();
    const float4* src4 = (const float4*)(emb + c*128*64);
    #pragma unroll
    for (int i = 0; i < 8; ++i) ((float4*)E)[t + i*256] = src4[t + i*256];
    __syncthreads();
    if (t < 128) {
      float s = 0.f;
      const float4* row = (const float4*)&E[t << 6];
      #pragma unroll
      for (int i = 0; i < 16; ++i) {
        float4 v = row[i]; s += v.x*v.x + v.y*v.y + v.z*v.z + v.w*v.w;
      }
      nrm[t] = s;
    }
    __syncthreads();
    for (int k = 0; k < 128; ++k) {
      const float4* row = (const float4*)&E[k << 6];
      float dot = 0.f;
      #pragma unroll
      for (int i = 0; i < 16; ++i) {
        float4 v = row[i];
        dot += v.x*x[4*i] + v.y*x[4*i+1] + v.z*x[4*i+2] + v.w*x[4*i+3];
      }
      float dist = nrm[k] - 2.f*dot;
      if (dist < best) { best = dist; bi = c*128 + k; }
    }
  }

  atomicAdd(&hist[bi], 1);
  float ls = 0.f;
  const float* er = emb + (bi << 6);
  u16* qb = quant + ((size_t)n << 18) + sp;
  #pragma unroll
  for (int d = 0; d < 64; ++d) {
    float e = er[d];
    qb[(size_t)d << 12] = f2bf(e);
    float df = e - x[d]; ls += df*df;
  }
  #pragma unroll
  for (int o = 32; o; o >>= 1) ls += __shfl_down(ls, o, 64);
  if ((t & 63) == 0) atomicAdd(loss_sum, ls);
}

__global__ void finalize_kernel(const int* __restrict__ hist,
                                const float* __restrict__ loss_sum,
                                float* __restrict__ out_loss,
                                float* __restrict__ out_perp) {
  __shared__ float red[512];
  int t = threadIdx.x;
  float pr = (float)hist[t] * (1.f/32768.f);
  red[t] = pr * logf(pr + 1e-10f);
  __syncthreads();
  for (int s = 256; s; s >>= 1) {
    if (t < s) red[t] += red[t + s];
    __syncthreads();
  }
  if (t == 0) {
    out_loss[0] = 1.25f * loss_sum[0] * (1.f/2097152.f);
    out_perp[0] = expf(-red[0]);
  }
}

// ===========================================================================
extern "C" void kernel_launch(void* const* d_in, const int* in_sizes, int n_in,
                              void* d_out, int out_size, void* d_ws, size_t ws_size,
                              hipStream_t stream) {
  (void)in_sizes; (void)n_in; (void)ws_size;
  const float* x   = (const float*)d_in[0];
  const float* ew1 = (const float*)d_in[1];
  const float* eb1 = (const float*)d_in[2];
  const float* ew2 = (const float*)d_in[3];
  const float* eb2 = (const float*)d_in[4];
  const float* pvw = (const float*)d_in[5];
  const float* pvb = (const float*)d_in[6];
  const float* emb = (const float*)d_in[7];
  const float* qvw = (const float*)d_in[8];
  const float* qvb = (const float*)d_in[9];
  const float* dw1 = (const float*)d_in[10];
  const float* db1 = (const float*)d_in[11];
  const float* dw2 = (const float*)d_in[12];
  const float* db2 = (const float*)d_in[13];
  float* out = (float*)d_out;

  char* ws = (char*)d_ws;
  float* h1   = (float*)(ws);                    // [8,128,128,128] f32, 67108864 B
  float* h2   = (float*)(ws + 67108864);         // [8,256,64,64] f32, 33554432 B
  float* ze   = (float*)(ws + 100663296);        // [8,64,64,64] f32, 8388608 B
  u16*   qz   = (u16*)  (ws + 109051904);        // [8,64,64,64] bf16, 4194304 B
  int*   hist = (int*)  (ws + 113246208);        // 2048 B
  float* lsum = (float*)(ws + 113248256);        // 64 B
  float* bt1  = (float*)(ws + 113248320);        // 24576 B
  float* bt2  = (float*)(ws + 113272896);        // 2097152 B
  float* btp  = (float*)(ws + 115370048);        // 65536 B
  u16*   btq  = (u16*)  (ws + 115435584);        // 294912 B
  u16*   btd  = (u16*)  (ws + 115730496);        // 1048576 B
  u16*   btd2 = (u16*)  (ws + 116779072);        // 65536 B
  u16* g  = (u16*)(ws + 67108864);  // bf16 postvq out, overlays h2 (dead)
  u16* g2 = (u16*)ws;               // bf16 deconv1 out, overlays h1 (dead)

  hipMemsetAsync(hist, 0, 2048 + 64, stream);
  prep_enc<<<2136, 256, 0, stream>>>(ew1, ew2, pvw, bt1, bt2, btp);
  prep_dec<<<2752, 256, 0, stream>>>(qvw, dw1, dw2, btq, btd, btd2);

  conv_f32<F_CONV1><<<1024, 256, 0, stream>>>(x,  bt1, eb1, h1);
  conv_f32<F_CONV2><<<1024, 256, 0, stream>>>(h1, bt2, eb2, h2);
  conv_f32<F_PREVQ><<<512,  256, 0, stream>>>(h2, btp, pvb, ze);

  vq_kernel<<<128, 256, 0, stream>>>(ze, emb, qz, hist, lsum);
  finalize_kernel<<<1, 512, 0, stream>>>(hist, lsum, out, out + (out_size - 1));

  conv_mfma<M_POSTVQ> <<<512, 256, 0, stream>>>(qz, btq, qvb, g);
  conv_mfma<M_DECONV1><<<dim3(256, 4), 256, 0, stream>>>(g, btd, db1, g2);
  conv_mfma<M_DECONV2><<<dim3(1024, 4), 256, 0, stream>>>(g2, btd2, db2, out + 1);
}

// Round 4
// 784.551 us; speedup vs baseline: 2.1985x; 1.5191x over previous
//
#include <hip/hip_runtime.h>
#include <math.h>

typedef unsigned short u16;
typedef unsigned int uint;
typedef __attribute__((ext_vector_type(8))) short bh8;   // 8 bf16 in 4 VGPRs
typedef __attribute__((ext_vector_type(4))) float f32x4;

#define DEV __device__ __forceinline__

DEV u16 f2bf(float x) {                       // fp32 -> bf16 RNE
  uint u = __builtin_bit_cast(uint, x);
  return (u16)((u + 0x7FFFu + ((u >> 16) & 1u)) >> 16);
}
DEV float bf2f(u16 h) { return __builtin_bit_cast(float, (uint)h << 16); }

union Pack { u16 u[8]; uint4 v; };

DEV uint2 pack4(float v0, float v1, float v2, float v3) {
  uint2 s;
  s.x = (uint)f2bf(v0) | ((uint)f2bf(v1) << 16);
  s.y = (uint)f2bf(v2) | ((uint)f2bf(v3) << 16);
  return s;
}

// ===========================================================================
// ENCODER stage 1/3: fp32 VALU implicit-GEMM (conv1, prevq — exact numerics).
// ===========================================================================
enum { F_CONV1, F_PREVQ };

template<int MODE> struct FCfg;
template<> struct FCfg<F_CONV1> { static constexpr int K=48,  BM=128, BN=128, NOC=128, RELU=1; };
template<> struct FCfg<F_PREVQ> { static constexpr int K=256, BM=64,  BN=64,  NOC=64,  RELU=0; };

template<int MODE>
DEV float gatherF(const float* __restrict__ src, int n, int h, int w, int k) {
  if constexpr (MODE == F_CONV1) {            // k = ic*16 + r
    int ic = k >> 4, r = k & 15;
    int ih = 2*h - 1 + (r >> 2), iw = 2*w - 1 + (r & 3);
    return ((unsigned)ih < 256u && (unsigned)iw < 256u)
      ? src[((n*3 + ic) << 16) + (ih << 8) + iw] : 0.f;
  } else {                                    // PREVQ: k = ic
    return src[((n*256 + k) << 12) + (h << 6) + w];
  }
}

template<int MODE>
__global__ __launch_bounds__(256, 4) void conv_f32(const float* __restrict__ src,
                                                   const float* __restrict__ Bt,
                                                   const float* __restrict__ bias,
                                                   float* __restrict__ out) {
  constexpr int K  = FCfg<MODE>::K,  BM = FCfg<MODE>::BM;
  constexpr int BN = FCfg<MODE>::BN, NOC = FCfg<MODE>::NOC;
  constexpr int NT = NOC / BN;
  constexpr int MH = BM / 64, NH = BN / 64;
  constexpr int AE = 16*BM/256, KS = 256/BM;

  __shared__ __align__(16) float As[16*BM];
  __shared__ __align__(16) float Bs[16*BN];

  const int t = threadIdx.x;
  const int nt = (NT > 1) ? (int)(blockIdx.x % NT) : 0;
  const int mt = (NT > 1) ? (int)(blockIdx.x / NT) : (int)blockIdx.x;

  const int pl = t & (BM-1), kb = t / BM;
  const int p = mt*BM + pl;
  int n, h, w;
  if constexpr (MODE == F_CONV1) { n = p >> 14; h = (p >> 7) & 127; w = p & 127; }
  else                           { n = p >> 12; h = (p >> 6) & 63;  w = p & 63;  }

  const int ti = t & 15, tj = t >> 4;

  float acc[MH*4][NH*4];
  #pragma unroll
  for (int i = 0; i < MH*4; ++i)
    #pragma unroll
    for (int j = 0; j < NH*4; ++j) acc[i][j] = 0.f;

  for (int k0 = 0; k0 < K; k0 += 16) {
    #pragma unroll
    for (int jj = 0; jj < AE; ++jj) {
      int kr = jj*KS + kb;
      As[kr*BM + pl] = gatherF<MODE>(src, n, h, w, k0 + kr);
    }
    #pragma unroll
    for (int jj = 0; jj < (16*BN/4)/256; ++jj) {
      int id = jj*256 + t;
      int kr = id / (BN/4), c4 = id % (BN/4);
      ((float4*)Bs)[kr*(BN/4) + c4] =
          *((const float4*)(Bt + (size_t)(k0 + kr)*NOC + nt*BN) + c4);
    }
    __syncthreads();
    #pragma unroll
    for (int kk = 0; kk < 16; ++kk) {
      float a[MH*4], b[NH*4];
      *(float4*)&a[0] = *(const float4*)&As[kk*BM + ti*4];
      if constexpr (MH == 2) *(float4*)&a[4] = *(const float4*)&As[kk*BM + 64 + ti*4];
      *(float4*)&b[0] = *(const float4*)&Bs[kk*BN + tj*4];
      if constexpr (NH == 2) *(float4*)&b[4] = *(const float4*)&Bs[kk*BN + 64 + tj*4];
      #pragma unroll
      for (int i = 0; i < MH*4; ++i)
        #pragma unroll
        for (int j = 0; j < NH*4; ++j)
          acc[i][j] += a[i]*b[j];
    }
    __syncthreads();
  }

  #pragma unroll
  for (int i = 0; i < MH*4; ++i) {
    int pp = mt*BM + (i>>2)*64 + ti*4 + (i&3);
    int nn, hh, ww;
    if constexpr (MODE == F_CONV1) { nn = pp >> 14; hh = (pp >> 7) & 127; ww = pp & 127; }
    else                           { nn = pp >> 12; hh = (pp >> 6) & 63;  ww = pp & 63;  }
    #pragma unroll
    for (int j = 0; j < NH*4; ++j) {
      int oc = nt*BN + (j>>2)*64 + tj*4 + (j&3);
      float v = acc[i][j] + bias[oc];
      if constexpr (FCfg<MODE>::RELU) v = fmaxf(v, 0.f);
      if constexpr (MODE == F_CONV1)
        out[((nn*128 + oc) << 14) + (hh << 7) + ww] = v;
      else
        out[((nn*64 + oc) << 12) + (hh << 6) + ww] = v;
    }
  }
}

// ===========================================================================
// ENCODER stage 2/3: conv2 via bf16x3 split-precision MFMA (fp32-accurate).
// M=32768 px, N=256, K=2048 (k = tap*128 + ic). 128x128 tile, BK=64.
// acc += Ah*Bh + Al*Bh + Ah*Bl  (lo*lo dropped: ~2^-17 relative)
// ===========================================================================
__global__ __launch_bounds__(256, 2) void conv2_mfma3(const float* __restrict__ src,
                                                      const u16* __restrict__ Bh,
                                                      const u16* __restrict__ Bl,
                                                      const float* __restrict__ bias,
                                                      float* __restrict__ out) {
  __shared__ u16 Ah[128*72], Al[128*72], Bhs[128*72], Bls[128*72];

  const int t = threadIdx.x;
  const int nt = blockIdx.x & 1, mt = blockIdx.x >> 1;
  const int pl = t & 127, kb = t >> 7;
  const int p = mt*128 + pl;
  const int n = p >> 12, h = (p >> 6) & 63, w = p & 63;
  const int lane = t & 63, wv = t >> 6;
  const int lr = lane & 15, lg = lane >> 4;
  const int wm = wv & 1, wn = wv >> 1;

  f32x4 acc[4][4];
  #pragma unroll
  for (int fm = 0; fm < 4; ++fm)
    #pragma unroll
    for (int fn = 0; fn < 4; ++fn)
      #pragma unroll
      for (int q = 0; q < 4; ++q) acc[fm][fn][q] = 0.f;

  for (int k0 = 0; k0 < 2048; k0 += 64) {
    __syncthreads();
    // ---- A: gather fp32, split hi/lo ----
    const int r = k0 >> 7, icb = (k0 & 127) + kb*32;
    const int ih = 2*h - 1 + (r >> 2), iw = 2*w - 1 + (r & 3);
    const bool ok = ((unsigned)ih < 128u) && ((unsigned)iw < 128u);
    const float* sb = src + ((size_t)((n*128 + icb)) << 14) + (ih << 7) + iw;
    Pack ph[4], pl4[4];
    #pragma unroll
    for (int jj = 0; jj < 32; ++jj) {
      float v = ok ? sb[(size_t)jj << 14] : 0.f;
      u16 hi = f2bf(v);
      u16 lo = f2bf(v - bf2f(hi));
      ph[jj >> 3].u[jj & 7]  = hi;
      pl4[jj >> 3].u[jj & 7] = lo;
    }
    #pragma unroll
    for (int i = 0; i < 4; ++i) {
      *(uint4*)&Ah[pl*72 + kb*32 + i*8] = ph[i].v;
      *(uint4*)&Al[pl*72 + kb*32 + i*8] = pl4[i].v;
    }
    // ---- B: coalesced hi/lo [oc][2048] ----
    #pragma unroll
    for (int i = 0; i < 4; ++i) {
      int id = i*256 + t, oc = id >> 3, ch = id & 7;
      size_t bo = (size_t)(nt*128 + oc)*2048 + k0 + ch*8;
      *(uint4*)&Bhs[oc*72 + ch*8] = *(const uint4*)(Bh + bo);
      *(uint4*)&Bls[oc*72 + ch*8] = *(const uint4*)(Bl + bo);
    }
    __syncthreads();
    // ---- MFMA: 3 passes ----
    #pragma unroll
    for (int ks = 0; ks < 2; ++ks) {
      bh8 afh[4], afl[4];
      #pragma unroll
      for (int fm = 0; fm < 4; ++fm) {
        afh[fm] = *(const bh8*)&Ah[(wm*64 + fm*16 + lr)*72 + ks*32 + lg*8];
        afl[fm] = *(const bh8*)&Al[(wm*64 + fm*16 + lr)*72 + ks*32 + lg*8];
      }
      #pragma unroll
      for (int fn = 0; fn < 4; ++fn) {
        bh8 bfh = *(const bh8*)&Bhs[(wn*64 + fn*16 + lr)*72 + ks*32 + lg*8];
        bh8 bfl = *(const bh8*)&Bls[(wn*64 + fn*16 + lr)*72 + ks*32 + lg*8];
        #pragma unroll
        for (int fm = 0; fm < 4; ++fm) {
          acc[fm][fn] = __builtin_amdgcn_mfma_f32_16x16x32_bf16(afh[fm], bfh, acc[fm][fn], 0,0,0);
          acc[fm][fn] = __builtin_amdgcn_mfma_f32_16x16x32_bf16(afl[fm], bfh, acc[fm][fn], 0,0,0);
          acc[fm][fn] = __builtin_amdgcn_mfma_f32_16x16x32_bf16(afh[fm], bfl, acc[fm][fn], 0,0,0);
        }
      }
    }
  }

  // ---- epilogue: bias + ReLU, fp32 out [n][oc 256][64][64] ----
  #pragma unroll
  for (int fm = 0; fm < 4; ++fm) {
    const int pq = mt*128 + wm*64 + fm*16 + lg*4;
    const int nn = pq >> 12, hwq = pq & 4095;
    #pragma unroll
    for (int fn = 0; fn < 4; ++fn) {
      const int oc = nt*128 + wn*64 + fn*16 + lr;
      const float bv = bias[oc];
      float v0 = fmaxf(acc[fm][fn][0] + bv, 0.f);
      float v1 = fmaxf(acc[fm][fn][1] + bv, 0.f);
      float v2 = fmaxf(acc[fm][fn][2] + bv, 0.f);
      float v3 = fmaxf(acc[fm][fn][3] + bv, 0.f);
      *(float4*)(out + (((size_t)(nn*256 + oc)) << 12) + hwq) = make_float4(v0,v1,v2,v3);
    }
  }
}

// ===========================================================================
// DECODER: bf16 MFMA implicit-GEMM (verified round-2/3). BM=128, BK=64.
// ===========================================================================
enum { M_POSTVQ, M_DECONV1, M_DECONV2 };

template<int MODE> struct Cfg;
template<> struct Cfg<M_POSTVQ> { static constexpr int K=576,  BN=128, NOC=256, RELU=0; };
template<> struct Cfg<M_DECONV1>{ static constexpr int K=1024, BN=128, NOC=128, RELU=1; };
template<> struct Cfg<M_DECONV2>{ static constexpr int K=512,  BN=16,  NOC=16,  RELU=0; };

template<int MODE>
__global__ __launch_bounds__(256, 2) void conv_mfma(const void* __restrict__ src_,
                                                    const u16* __restrict__ Bt,
                                                    const float* __restrict__ bias,
                                                    void* __restrict__ out_) {
  constexpr int K  = Cfg<MODE>::K;
  constexpr int BN = Cfg<MODE>::BN;
  constexpr int NOC = Cfg<MODE>::NOC;
  constexpr int NT = NOC / BN;
  constexpr int WM = (BN == 128) ? 2 : 4;
  constexpr int WN = (BN == 128) ? 2 : 1;
  constexpr int FM = 128 / WM / 16;
  constexpr int FN = BN / WN / 16;

  __shared__ u16 As[128 * 72];
  __shared__ u16 Bs[BN * 72];

  const int t = threadIdx.x;
  const int nt = (NT > 1) ? (int)(blockIdx.x % NT) : 0;
  const int mt = (NT > 1) ? (int)(blockIdx.x / NT) : (int)blockIdx.x;
  int par = 0;
  if constexpr (MODE == M_DECONV1 || MODE == M_DECONV2) {
    par = blockIdx.y;
    Bt += (size_t)par * NOC * K;
  }

  const int pl = t & 127, kb = t >> 7;
  const int p = mt * 128 + pl;
  int n, h, w;
  if constexpr (MODE == M_DECONV2) { n = p >> 14; h = (p >> 7) & 127; w = p & 127; }
  else                             { n = p >> 12; h = (p >> 6) & 63;  w = p & 63;  }

  const int lane = t & 63, wv = t >> 6;
  const int lr = lane & 15, lg = lane >> 4;
  const int wm = (WM == 2) ? (wv & 1) : wv;
  const int wn = (WM == 2) ? (wv >> 1) : 0;

  f32x4 acc[FM][FN];
  #pragma unroll
  for (int fm = 0; fm < FM; ++fm)
    #pragma unroll
    for (int fn = 0; fn < FN; ++fn)
      #pragma unroll
      for (int q = 0; q < 4; ++q) acc[fm][fn][q] = 0.f;

  const u16* srcu = (const u16*)src_;

  for (int k0 = 0; k0 < K; k0 += 64) {
    __syncthreads();
    Pack pk[4];
    if constexpr (MODE == M_DECONV2) {
      int tap = k0 >> 7, icb = k0 & 127;
      int j1 = tap >> 1, j0 = tap & 1;
      int qy = par >> 1, qx = par & 1;
      int ih = h - 1 + qy + j1, iw = w - 1 + qx + j0;
      bool ok = ((unsigned)ih < 128u) && ((unsigned)iw < 128u);
      int ipar = ((ih & 1) << 1) | (iw & 1);
      const u16* sb = srcu + ((((size_t)(n*4 + ipar)) << 12) + ((ih >> 1) << 6) + (iw >> 1)) * 128
                          + icb + kb * 32;
      #pragma unroll
      for (int i = 0; i < 4; ++i)
        pk[i].v = ok ? *(const uint4*)(sb + i*8) : make_uint4(0,0,0,0);
    } else {
      const u16* sb; bool ok = true;
      if constexpr (MODE == M_POSTVQ) {
        int r = k0 >> 6, kh = r / 3, kw = r - 3*kh;
        int ih = h - 1 + kh, iw = w - 1 + kw;
        ok = ((unsigned)ih < 64u) && ((unsigned)iw < 64u);
        sb = srcu + (size_t)(((n << 6) + kb*32) << 12) + (ih << 6) + iw;
      } else { // M_DECONV1
        int j = k0 >> 8, icb = k0 & 255;
        int j1 = j >> 1, j0 = j & 1;
        int py = par >> 1, px = par & 1;
        int ih = h + py - 1 + j1, iw = w + px - 1 + j0;
        ok = ((unsigned)ih < 64u) && ((unsigned)iw < 64u);
        sb = srcu + (size_t)((n*256 + icb + kb*32) << 12) + (ih << 6) + iw;
      }
      #pragma unroll
      for (int jj = 0; jj < 32; ++jj) {
        u16 v = ok ? sb[(size_t)jj * 4096] : (u16)0;
        pk[jj >> 3].u[jj & 7] = v;
      }
    }
    #pragma unroll
    for (int i = 0; i < 4; ++i)
      *(uint4*)&As[pl*72 + kb*32 + i*8] = pk[i].v;

    constexpr int NBI = (BN*8 + 255) / 256;
    #pragma unroll
    for (int i = 0; i < NBI; ++i) {
      int id = i*256 + t;
      bool okb = true;
      if constexpr ((BN*8) % 256 != 0) okb = (id < BN*8);
      if (okb) {
        int oc = id >> 3, ch = id & 7;
        *(uint4*)&Bs[oc*72 + ch*8] = *(const uint4*)(Bt + (size_t)oc*K + k0 + ch*8);
      }
    }
    __syncthreads();

    #pragma unroll
    for (int ks = 0; ks < 2; ++ks) {
      bh8 af[FM];
      #pragma unroll
      for (int fm = 0; fm < FM; ++fm)
        af[fm] = *(const bh8*)&As[(wm*(128/WM) + fm*16 + lr)*72 + ks*32 + lg*8];
      #pragma unroll
      for (int fn = 0; fn < FN; ++fn) {
        bh8 bf = *(const bh8*)&Bs[(wn*(BN/WN) + fn*16 + lr)*72 + ks*32 + lg*8];
        #pragma unroll
        for (int fm = 0; fm < FM; ++fm)
          acc[fm][fn] = __builtin_amdgcn_mfma_f32_16x16x32_bf16(af[fm], bf, acc[fm][fn], 0, 0, 0);
      }
    }
  }

  u16*   outu = (u16*)out_;
  float* outf = (float*)out_;
  #pragma unroll
  for (int fm = 0; fm < FM; ++fm) {
    const int pq = mt*128 + wm*(128/WM) + fm*16 + lg*4;
    int nn, hwq;
    if constexpr (MODE == M_DECONV2) { nn = pq >> 14; hwq = pq & 16383; }
    else                             { nn = pq >> 12; hwq = pq & 4095;  }
    #pragma unroll
    for (int fn = 0; fn < FN; ++fn) {
      const int oc = nt*BN + wn*(BN/WN) + fn*16 + lr;
      float bvv;
      if constexpr (MODE == M_DECONV2) bvv = (lr < 3) ? bias[oc] : 0.f;
      else                             bvv = bias[oc];
      float v0 = acc[fm][fn][0] + bvv, v1 = acc[fm][fn][1] + bvv;
      float v2 = acc[fm][fn][2] + bvv, v3 = acc[fm][fn][3] + bvv;
      if constexpr (Cfg<MODE>::RELU) {
        v0 = fmaxf(v0, 0.f); v1 = fmaxf(v1, 0.f); v2 = fmaxf(v2, 0.f); v3 = fmaxf(v3, 0.f);
      }
      if constexpr (MODE == M_POSTVQ) {
        *(uint2*)(outu + (((size_t)(nn*256 + oc)) << 12) + hwq) = pack4(v0,v1,v2,v3);
      } else if constexpr (MODE == M_DECONV1) {
        u16* ob = outu + (((size_t)(nn*4 + par)) << 19) + (size_t)hwq * 128 + oc;
        ob[0]   = f2bf(v0);
        ob[128] = f2bf(v1);
        ob[256] = f2bf(v2);
        ob[384] = f2bf(v3);
      } else { // M_DECONV2 -> x_recon fp32
        if (lr < 3) {
          const int hq = (pq >> 7) & 127, wq = pq & 127;
          const int qy = par >> 1, qx = par & 1;
          const int oh = 2*hq + qy;
          float* ob = outf + (((size_t)(nn*3 + oc)) << 16) + (oh << 8) + qx;
          ob[2*wq]     = v0;
          ob[2*wq + 2] = v1;
          ob[2*wq + 4] = v2;
          ob[2*wq + 6] = v3;
        }
      }
    }
  }
}

// ===========================================================================
// Weight preps
// ===========================================================================
__global__ void prep_enc(const float* __restrict__ ew1, const float* __restrict__ ew2,
                         const float* __restrict__ pvw,
                         float* bt1, u16* bt2h, u16* bt2l, float* btp) {
  int i = blockIdx.x * 256 + threadIdx.x;
  if (i < 6144) {                               // bt1 [k=ic*16+r][128]
    int k = i >> 7, oc = i & 127;
    bt1[i] = ew1[oc*48 + k];
  } else if ((i -= 6144) < 524288) {            // bt2h/l [oc][k=tap*128+ic] bf16
    int oc = i >> 11, k = i & 2047;
    int r = k >> 7, ic = k & 127;
    float v = ew2[oc*2048 + ic*16 + r];
    u16 hi = f2bf(v);
    bt2h[i] = hi;
    bt2l[i] = f2bf(v - bf2f(hi));
  } else if ((i -= 524288) < 16384) {           // btp [k][64]
    int k = i >> 6, oc = i & 63;
    btp[i] = pvw[oc*256 + k];
  }
}

__global__ void prep_dec(const float* __restrict__ qvw, const float* __restrict__ dw1,
                         const float* __restrict__ dw2,
                         u16* btq, u16* btd, u16* btd2) {
  int i = blockIdx.x * 256 + threadIdx.x;
  if (i < 147456) {                             // btq [oc][k=r*64+ic]
    int oc = i / 576, rem = i - oc*576, r = rem >> 6, ic = rem & 63;
    btq[i] = f2bf(qvw[oc*576 + ic*9 + r]);
  } else if ((i -= 147456) < 524288) {          // btd [par][oc][k=j*256+ic]
    int pr = i >> 17, oc = (i >> 10) & 127, j = (i >> 8) & 3, ic = i & 255;
    int py = pr >> 1, px = pr & 1, j1 = j >> 1, j0 = j & 1;
    btd[i] = f2bf(dw1[oc*4096 + ic*16 + (py + 2*j1)*4 + (px + 2*j0)]);
  } else if ((i -= 524288) < 32768) {           // btd2 [q][oc16][k=tap*128+ic]
    int q = i >> 13, oc = (i >> 9) & 15, tap = (i >> 7) & 3, ic = i & 127;
    int qy = q >> 1, qx = q & 1, j1 = tap >> 1, j0 = tap & 1;
    btd2[i] = (oc < 3) ? f2bf(dw2[oc*2048 + ic*16 + (qy + 2*j1)*4 + (qx + 2*j0)]) : (u16)0;
  }
}

// ===========================================================================
// VQ: fp32-exact argmin + quantize (+ bf16 qz for decoder) + loss/hist
// ===========================================================================
__global__ __launch_bounds__(256, 2) void vq_kernel(const float* __restrict__ ze,
                                                    const float* __restrict__ emb,
                                                    u16* __restrict__ quant,
                                                    int* __restrict__ hist,
                                                    float* __restrict__ loss_sum) {
  __shared__ __align__(16) float E[128*64];
  __shared__ float nrm[128];
  int t = threadIdx.x;
  int p = blockIdx.x*256 + t;
  int n = p >> 12, sp = p & 4095;
  const float* zb = ze + ((size_t)n << 18) + sp;
  float x[64];
  #pragma unroll
  for (int d = 0; d < 64; ++d) x[d] = zb[(size_t)d << 12];

  float best = 3.402823466e38f; int bi = 0;
  for (int c = 0; c < 4; ++c) {
    __syncthreads();
    const float4* src4 = (const float4*)(emb + c*128*64);
    #pragma unroll
    for (int i = 0; i < 8; ++i) ((float4*)E)[t + i*256] = src4[t + i*256];
    __syncthreads();
    if (t < 128) {
      float s = 0.f;
      const float4* row = (const float4*)&E[t << 6];
      #pragma unroll
      for (int i = 0; i < 16; ++i) {
        float4 v = row[i]; s += v.x*v.x + v.y*v.y + v.z*v.z + v.w*v.w;
      }
      nrm[t] = s;
    }
    __syncthreads();
    for (int k = 0; k < 128; ++k) {
      const float4* row = (const float4*)&E[k << 6];
      float dot = 0.f;
      #pragma unroll
      for (int i = 0; i < 16; ++i) {
        float4 v = row[i];
        dot += v.x*x[4*i] + v.y*x[4*i+1] + v.z*x[4*i+2] + v.w*x[4*i+3];
      }
      float dist = nrm[k] - 2.f*dot;
      if (dist < best) { best = dist; bi = c*128 + k; }
    }
  }

  atomicAdd(&hist[bi], 1);
  float ls = 0.f;
  const float* er = emb + (bi << 6);
  u16* qb = quant + ((size_t)n << 18) + sp;
  #pragma unroll
  for (int d = 0; d < 64; ++d) {
    float e = er[d];
    qb[(size_t)d << 12] = f2bf(e);
    float df = e - x[d]; ls += df*df;
  }
  #pragma unroll
  for (int o = 32; o; o >>= 1) ls += __shfl_down(ls, o, 64);
  if ((t & 63) == 0) atomicAdd(loss_sum, ls);
}

__global__ void finalize_kernel(const int* __restrict__ hist,
                                const float* __restrict__ loss_sum,
                                float* __restrict__ out_loss,
                                float* __restrict__ out_perp) {
  __shared__ float red[512];
  int t = threadIdx.x;
  float pr = (float)hist[t] * (1.f/32768.f);
  red[t] = pr * logf(pr + 1e-10f);
  __syncthreads();
  for (int s = 256; s; s >>= 1) {
    if (t < s) red[t] += red[t + s];
    __syncthreads();
  }
  if (t == 0) {
    out_loss[0] = 1.25f * loss_sum[0] * (1.f/2097152.f);
    out_perp[0] = expf(-red[0]);
  }
}

// ===========================================================================
extern "C" void kernel_launch(void* const* d_in, const int* in_sizes, int n_in,
                              void* d_out, int out_size, void* d_ws, size_t ws_size,
                              hipStream_t stream) {
  (void)in_sizes; (void)n_in; (void)ws_size;
  const float* x   = (const float*)d_in[0];
  const float* ew1 = (const float*)d_in[1];
  const float* eb1 = (const float*)d_in[2];
  const float* ew2 = (const float*)d_in[3];
  const float* eb2 = (const float*)d_in[4];
  const float* pvw = (const float*)d_in[5];
  const float* pvb = (const float*)d_in[6];
  const float* emb = (const float*)d_in[7];
  const float* qvw = (const float*)d_in[8];
  const float* qvb = (const float*)d_in[9];
  const float* dw1 = (const float*)d_in[10];
  const float* db1 = (const float*)d_in[11];
  const float* dw2 = (const float*)d_in[12];
  const float* db2 = (const float*)d_in[13];
  float* out = (float*)d_out;

  char* ws = (char*)d_ws;
  float* h1   = (float*)(ws);                    // [8,128,128,128] f32, 67108864 B
  float* h2   = (float*)(ws + 67108864);         // [8,256,64,64] f32, 33554432 B
  float* ze   = (float*)(ws + 100663296);        // [8,64,64,64] f32, 8388608 B
  u16*   qz   = (u16*)  (ws + 109051904);        // [8,64,64,64] bf16, 4194304 B
  int*   hist = (int*)  (ws + 113246208);        // 2048 B
  float* lsum = (float*)(ws + 113248256);        // 64 B
  float* bt1  = (float*)(ws + 113248320);        // 24576 B
  float* btp  = (float*)(ws + 113272896);        // 65536 B
  u16*   bt2h = (u16*)  (ws + 113338432);        // 1048576 B
  u16*   bt2l = (u16*)  (ws + 114387008);        // 1048576 B
  u16*   btq  = (u16*)  (ws + 115435584);        // 294912 B
  u16*   btd  = (u16*)  (ws + 115730496);        // 1048576 B
  u16*   btd2 = (u16*)  (ws + 116779072);        // 65536 B
  u16* g  = (u16*)(ws + 67108864);  // bf16 postvq out, overlays h2 (dead)
  u16* g2 = (u16*)ws;               // bf16 deconv1 out, overlays h1 (dead)

  hipMemsetAsync(hist, 0, 2048 + 64, stream);
  prep_enc<<<2136, 256, 0, stream>>>(ew1, ew2, pvw, bt1, bt2h, bt2l, btp);
  prep_dec<<<2752, 256, 0, stream>>>(qvw, dw1, dw2, btq, btd, btd2);

  conv_f32<F_CONV1><<<1024, 256, 0, stream>>>(x,  bt1, eb1, h1);
  conv2_mfma3<<<512, 256, 0, stream>>>(h1, bt2h, bt2l, eb2, h2);
  conv_f32<F_PREVQ><<<512,  256, 0, stream>>>(h2, btp, pvb, ze);

  vq_kernel<<<128, 256, 0, stream>>>(ze, emb, qz, hist, lsum);
  finalize_kernel<<<1, 512, 0, stream>>>(hist, lsum, out, out + (out_size - 1));

  conv_mfma<M_POSTVQ> <<<512, 256, 0, stream>>>(qz, btq, qvb, g);
  conv_mfma<M_DECONV1><<<dim3(256, 4), 256, 0, stream>>>(g, btd, db1, g2);
  conv_mfma<M_DECONV2><<<dim3(1024, 4), 256, 0, stream>>>(g2, btd2, db2, out + 1);
}

// Round 5
// 572.879 us; speedup vs baseline: 3.0109x; 1.3695x over previous
//
#include <hip/hip_runtime.h>
#include <math.h>

typedef unsigned short u16;
typedef unsigned int uint;
typedef __attribute__((ext_vector_type(8))) short bh8;   // 8 bf16 in 4 VGPRs
typedef __attribute__((ext_vector_type(4))) float f32x4;

#define DEV __device__ __forceinline__

DEV u16 f2bf(float x) {                       // fp32 -> bf16 RNE
  uint u = __builtin_bit_cast(uint, x);
  return (u16)((u + 0x7FFFu + ((u >> 16) & 1u)) >> 16);
}
DEV float bf2f(u16 h) { return __builtin_bit_cast(float, (uint)h << 16); }

union Pack { u16 u[8]; uint4 v; };

DEV uint2 pack4(float v0, float v1, float v2, float v3) {
  uint2 s;
  s.x = (uint)f2bf(v0) | ((uint)f2bf(v1) << 16);
  s.y = (uint)f2bf(v2) | ((uint)f2bf(v3) << 16);
  return s;
}

// ===========================================================================
// ENCODER stage 1/3: fp32 VALU implicit-GEMM (conv1, prevq — exact numerics).
// ===========================================================================
enum { F_CONV1, F_PREVQ };

template<int MODE> struct FCfg;
template<> struct FCfg<F_CONV1> { static constexpr int K=48,  BM=128, BN=128, NOC=128, RELU=1; };
template<> struct FCfg<F_PREVQ> { static constexpr int K=256, BM=64,  BN=64,  NOC=64,  RELU=0; };

template<int MODE>
DEV float gatherF(const float* __restrict__ src, int n, int h, int w, int k) {
  if constexpr (MODE == F_CONV1) {            // k = ic*16 + r
    int ic = k >> 4, r = k & 15;
    int ih = 2*h - 1 + (r >> 2), iw = 2*w - 1 + (r & 3);
    return ((unsigned)ih < 256u && (unsigned)iw < 256u)
      ? src[((n*3 + ic) << 16) + (ih << 8) + iw] : 0.f;
  } else {                                    // PREVQ: k = ic
    return src[((n*256 + k) << 12) + (h << 6) + w];
  }
}

template<int MODE>
__global__ __launch_bounds__(256, 4) void conv_f32(const float* __restrict__ src,
                                                   const float* __restrict__ Bt,
                                                   const float* __restrict__ bias,
                                                   float* __restrict__ out) {
  constexpr int K  = FCfg<MODE>::K,  BM = FCfg<MODE>::BM;
  constexpr int BN = FCfg<MODE>::BN, NOC = FCfg<MODE>::NOC;
  constexpr int NT = NOC / BN;
  constexpr int MH = BM / 64, NH = BN / 64;
  constexpr int AE = 16*BM/256, KS = 256/BM;

  __shared__ __align__(16) float As[16*BM];
  __shared__ __align__(16) float Bs[16*BN];

  const int t = threadIdx.x;
  const int nt = (NT > 1) ? (int)(blockIdx.x % NT) : 0;
  const int mt = (NT > 1) ? (int)(blockIdx.x / NT) : (int)blockIdx.x;

  const int pl = t & (BM-1), kb = t / BM;
  const int p = mt*BM + pl;
  int n, h, w;
  if constexpr (MODE == F_CONV1) { n = p >> 14; h = (p >> 7) & 127; w = p & 127; }
  else                           { n = p >> 12; h = (p >> 6) & 63;  w = p & 63;  }

  const int ti = t & 15, tj = t >> 4;

  float acc[MH*4][NH*4];
  #pragma unroll
  for (int i = 0; i < MH*4; ++i)
    #pragma unroll
    for (int j = 0; j < NH*4; ++j) acc[i][j] = 0.f;

  for (int k0 = 0; k0 < K; k0 += 16) {
    #pragma unroll
    for (int jj = 0; jj < AE; ++jj) {
      int kr = jj*KS + kb;
      As[kr*BM + pl] = gatherF<MODE>(src, n, h, w, k0 + kr);
    }
    #pragma unroll
    for (int jj = 0; jj < (16*BN/4)/256; ++jj) {
      int id = jj*256 + t;
      int kr = id / (BN/4), c4 = id % (BN/4);
      ((float4*)Bs)[kr*(BN/4) + c4] =
          *((const float4*)(Bt + (size_t)(k0 + kr)*NOC + nt*BN) + c4);
    }
    __syncthreads();
    #pragma unroll
    for (int kk = 0; kk < 16; ++kk) {
      float a[MH*4], b[NH*4];
      *(float4*)&a[0] = *(const float4*)&As[kk*BM + ti*4];
      if constexpr (MH == 2) *(float4*)&a[4] = *(const float4*)&As[kk*BM + 64 + ti*4];
      *(float4*)&b[0] = *(const float4*)&Bs[kk*BN + tj*4];
      if constexpr (NH == 2) *(float4*)&b[4] = *(const float4*)&Bs[kk*BN + 64 + tj*4];
      #pragma unroll
      for (int i = 0; i < MH*4; ++i)
        #pragma unroll
        for (int j = 0; j < NH*4; ++j)
          acc[i][j] += a[i]*b[j];
    }
    __syncthreads();
  }

  #pragma unroll
  for (int i = 0; i < MH*4; ++i) {
    int pp = mt*BM + (i>>2)*64 + ti*4 + (i&3);
    int nn, hh, ww;
    if constexpr (MODE == F_CONV1) { nn = pp >> 14; hh = (pp >> 7) & 127; ww = pp & 127; }
    else                           { nn = pp >> 12; hh = (pp >> 6) & 63;  ww = pp & 63;  }
    #pragma unroll
    for (int j = 0; j < NH*4; ++j) {
      int oc = nt*BN + (j>>2)*64 + tj*4 + (j&3);
      float v = acc[i][j] + bias[oc];
      if constexpr (FCfg<MODE>::RELU) v = fmaxf(v, 0.f);
      if constexpr (MODE == F_CONV1)
        out[((nn*128 + oc) << 14) + (hh << 7) + ww] = v;
      else
        out[((nn*64 + oc) << 12) + (hh << 6) + ww] = v;
    }
  }
}

// ===========================================================================
// ENCODER stage 2/3: conv2 via bf16x3 split-precision MFMA (fp32-accurate).
// ===========================================================================
__global__ __launch_bounds__(256, 2) void conv2_mfma3(const float* __restrict__ src,
                                                      const u16* __restrict__ Bh,
                                                      const u16* __restrict__ Bl,
                                                      const float* __restrict__ bias,
                                                      float* __restrict__ out) {
  __shared__ u16 Ah[128*72], Al[128*72], Bhs[128*72], Bls[128*72];

  const int t = threadIdx.x;
  const int nt = blockIdx.x & 1, mt = blockIdx.x >> 1;
  const int pl = t & 127, kb = t >> 7;
  const int p = mt*128 + pl;
  const int n = p >> 12, h = (p >> 6) & 63, w = p & 63;
  const int lane = t & 63, wv = t >> 6;
  const int lr = lane & 15, lg = lane >> 4;
  const int wm = wv & 1, wn = wv >> 1;

  f32x4 acc[4][4];
  #pragma unroll
  for (int fm = 0; fm < 4; ++fm)
    #pragma unroll
    for (int fn = 0; fn < 4; ++fn)
      #pragma unroll
      for (int q = 0; q < 4; ++q) acc[fm][fn][q] = 0.f;

  for (int k0 = 0; k0 < 2048; k0 += 64) {
    __syncthreads();
    const int r = k0 >> 7, icb = (k0 & 127) + kb*32;
    const int ih = 2*h - 1 + (r >> 2), iw = 2*w - 1 + (r & 3);
    const bool ok = ((unsigned)ih < 128u) && ((unsigned)iw < 128u);
    const float* sb = src + ((size_t)((n*128 + icb)) << 14) + (ih << 7) + iw;
    Pack ph[4], pl4[4];
    #pragma unroll
    for (int jj = 0; jj < 32; ++jj) {
      float v = ok ? sb[(size_t)jj << 14] : 0.f;
      u16 hi = f2bf(v);
      u16 lo = f2bf(v - bf2f(hi));
      ph[jj >> 3].u[jj & 7]  = hi;
      pl4[jj >> 3].u[jj & 7] = lo;
    }
    #pragma unroll
    for (int i = 0; i < 4; ++i) {
      *(uint4*)&Ah[pl*72 + kb*32 + i*8] = ph[i].v;
      *(uint4*)&Al[pl*72 + kb*32 + i*8] = pl4[i].v;
    }
    #pragma unroll
    for (int i = 0; i < 4; ++i) {
      int id = i*256 + t, oc = id >> 3, ch = id & 7;
      size_t bo = (size_t)(nt*128 + oc)*2048 + k0 + ch*8;
      *(uint4*)&Bhs[oc*72 + ch*8] = *(const uint4*)(Bh + bo);
      *(uint4*)&Bls[oc*72 + ch*8] = *(const uint4*)(Bl + bo);
    }
    __syncthreads();
    #pragma unroll
    for (int ks = 0; ks < 2; ++ks) {
      bh8 afh[4], afl[4];
      #pragma unroll
      for (int fm = 0; fm < 4; ++fm) {
        afh[fm] = *(const bh8*)&Ah[(wm*64 + fm*16 + lr)*72 + ks*32 + lg*8];
        afl[fm] = *(const bh8*)&Al[(wm*64 + fm*16 + lr)*72 + ks*32 + lg*8];
      }
      #pragma unroll
      for (int fn = 0; fn < 4; ++fn) {
        bh8 bfh = *(const bh8*)&Bhs[(wn*64 + fn*16 + lr)*72 + ks*32 + lg*8];
        bh8 bfl = *(const bh8*)&Bls[(wn*64 + fn*16 + lr)*72 + ks*32 + lg*8];
        #pragma unroll
        for (int fm = 0; fm < 4; ++fm) {
          acc[fm][fn] = __builtin_amdgcn_mfma_f32_16x16x32_bf16(afh[fm], bfh, acc[fm][fn], 0,0,0);
          acc[fm][fn] = __builtin_amdgcn_mfma_f32_16x16x32_bf16(afl[fm], bfh, acc[fm][fn], 0,0,0);
          acc[fm][fn] = __builtin_amdgcn_mfma_f32_16x16x32_bf16(afh[fm], bfl, acc[fm][fn], 0,0,0);
        }
      }
    }
  }

  #pragma unroll
  for (int fm = 0; fm < 4; ++fm) {
    const int pq = mt*128 + wm*64 + fm*16 + lg*4;
    const int nn = pq >> 12, hwq = pq & 4095;
    #pragma unroll
    for (int fn = 0; fn < 4; ++fn) {
      const int oc = nt*128 + wn*64 + fn*16 + lr;
      const float bv = bias[oc];
      float v0 = fmaxf(acc[fm][fn][0] + bv, 0.f);
      float v1 = fmaxf(acc[fm][fn][1] + bv, 0.f);
      float v2 = fmaxf(acc[fm][fn][2] + bv, 0.f);
      float v3 = fmaxf(acc[fm][fn][3] + bv, 0.f);
      *(float4*)(out + (((size_t)(nn*256 + oc)) << 12) + hwq) = make_float4(v0,v1,v2,v3);
    }
  }
}

// ===========================================================================
// DECODER: bf16 MFMA implicit-GEMM (verified). BM=128, BK=64.
// ===========================================================================
enum { M_POSTVQ, M_DECONV1, M_DECONV2 };

template<int MODE> struct Cfg;
template<> struct Cfg<M_POSTVQ> { static constexpr int K=576,  BN=128, NOC=256, RELU=0; };
template<> struct Cfg<M_DECONV1>{ static constexpr int K=1024, BN=128, NOC=128, RELU=1; };
template<> struct Cfg<M_DECONV2>{ static constexpr int K=512,  BN=16,  NOC=16,  RELU=0; };

template<int MODE>
__global__ __launch_bounds__(256, 2) void conv_mfma(const void* __restrict__ src_,
                                                    const u16* __restrict__ Bt,
                                                    const float* __restrict__ bias,
                                                    void* __restrict__ out_) {
  constexpr int K  = Cfg<MODE>::K;
  constexpr int BN = Cfg<MODE>::BN;
  constexpr int NOC = Cfg<MODE>::NOC;
  constexpr int NT = NOC / BN;
  constexpr int WM = (BN == 128) ? 2 : 4;
  constexpr int WN = (BN == 128) ? 2 : 1;
  constexpr int FM = 128 / WM / 16;
  constexpr int FN = BN / WN / 16;

  __shared__ u16 As[128 * 72];
  __shared__ u16 Bs[BN * 72];

  const int t = threadIdx.x;
  const int nt = (NT > 1) ? (int)(blockIdx.x % NT) : 0;
  const int mt = (NT > 1) ? (int)(blockIdx.x / NT) : (int)blockIdx.x;
  int par = 0;
  if constexpr (MODE == M_DECONV1 || MODE == M_DECONV2) {
    par = blockIdx.y;
    Bt += (size_t)par * NOC * K;
  }

  const int pl = t & 127, kb = t >> 7;
  const int p = mt * 128 + pl;
  int n, h, w;
  if constexpr (MODE == M_DECONV2) { n = p >> 14; h = (p >> 7) & 127; w = p & 127; }
  else                             { n = p >> 12; h = (p >> 6) & 63;  w = p & 63;  }

  const int lane = t & 63, wv = t >> 6;
  const int lr = lane & 15, lg = lane >> 4;
  const int wm = (WM == 2) ? (wv & 1) : wv;
  const int wn = (WM == 2) ? (wv >> 1) : 0;

  f32x4 acc[FM][FN];
  #pragma unroll
  for (int fm = 0; fm < FM; ++fm)
    #pragma unroll
    for (int fn = 0; fn < FN; ++fn)
      #pragma unroll
      for (int q = 0; q < 4; ++q) acc[fm][fn][q] = 0.f;

  const u16* srcu = (const u16*)src_;

  for (int k0 = 0; k0 < K; k0 += 64) {
    __syncthreads();
    Pack pk[4];
    if constexpr (MODE == M_DECONV2) {
      int tap = k0 >> 7, icb = k0 & 127;
      int j1 = tap >> 1, j0 = tap & 1;
      int qy = par >> 1, qx = par & 1;
      int ih = h - 1 + qy + j1, iw = w - 1 + qx + j0;
      bool ok = ((unsigned)ih < 128u) && ((unsigned)iw < 128u);
      int ipar = ((ih & 1) << 1) | (iw & 1);
      const u16* sb = srcu + ((((size_t)(n*4 + ipar)) << 12) + ((ih >> 1) << 6) + (iw >> 1)) * 128
                          + icb + kb * 32;
      #pragma unroll
      for (int i = 0; i < 4; ++i)
        pk[i].v = ok ? *(const uint4*)(sb + i*8) : make_uint4(0,0,0,0);
    } else {
      const u16* sb; bool ok = true;
      if constexpr (MODE == M_POSTVQ) {
        int r = k0 >> 6, kh = r / 3, kw = r - 3*kh;
        int ih = h - 1 + kh, iw = w - 1 + kw;
        ok = ((unsigned)ih < 64u) && ((unsigned)iw < 64u);
        sb = srcu + (size_t)(((n << 6) + kb*32) << 12) + (ih << 6) + iw;
      } else { // M_DECONV1
        int j = k0 >> 8, icb = k0 & 255;
        int j1 = j >> 1, j0 = j & 1;
        int py = par >> 1, px = par & 1;
        int ih = h + py - 1 + j1, iw = w + px - 1 + j0;
        ok = ((unsigned)ih < 64u) && ((unsigned)iw < 64u);
        sb = srcu + (size_t)((n*256 + icb + kb*32) << 12) + (ih << 6) + iw;
      }
      #pragma unroll
      for (int jj = 0; jj < 32; ++jj) {
        u16 v = ok ? sb[(size_t)jj * 4096] : (u16)0;
        pk[jj >> 3].u[jj & 7] = v;
      }
    }
    #pragma unroll
    for (int i = 0; i < 4; ++i)
      *(uint4*)&As[pl*72 + kb*32 + i*8] = pk[i].v;

    constexpr int NBI = (BN*8 + 255) / 256;
    #pragma unroll
    for (int i = 0; i < NBI; ++i) {
      int id = i*256 + t;
      bool okb = true;
      if constexpr ((BN*8) % 256 != 0) okb = (id < BN*8);
      if (okb) {
        int oc = id >> 3, ch = id & 7;
        *(uint4*)&Bs[oc*72 + ch*8] = *(const uint4*)(Bt + (size_t)oc*K + k0 + ch*8);
      }
    }
    __syncthreads();

    #pragma unroll
    for (int ks = 0; ks < 2; ++ks) {
      bh8 af[FM];
      #pragma unroll
      for (int fm = 0; fm < FM; ++fm)
        af[fm] = *(const bh8*)&As[(wm*(128/WM) + fm*16 + lr)*72 + ks*32 + lg*8];
      #pragma unroll
      for (int fn = 0; fn < FN; ++fn) {
        bh8 bf = *(const bh8*)&Bs[(wn*(BN/WN) + fn*16 + lr)*72 + ks*32 + lg*8];
        #pragma unroll
        for (int fm = 0; fm < FM; ++fm)
          acc[fm][fn] = __builtin_amdgcn_mfma_f32_16x16x32_bf16(af[fm], bf, acc[fm][fn], 0, 0, 0);
      }
    }
  }

  u16*   outu = (u16*)out_;
  float* outf = (float*)out_;
  #pragma unroll
  for (int fm = 0; fm < FM; ++fm) {
    const int pq = mt*128 + wm*(128/WM) + fm*16 + lg*4;
    int nn, hwq;
    if constexpr (MODE == M_DECONV2) { nn = pq >> 14; hwq = pq & 16383; }
    else                             { nn = pq >> 12; hwq = pq & 4095;  }
    #pragma unroll
    for (int fn = 0; fn < FN; ++fn) {
      const int oc = nt*BN + wn*(BN/WN) + fn*16 + lr;
      float bvv;
      if constexpr (MODE == M_DECONV2) bvv = (lr < 3) ? bias[oc] : 0.f;
      else                             bvv = bias[oc];
      float v0 = acc[fm][fn][0] + bvv, v1 = acc[fm][fn][1] + bvv;
      float v2 = acc[fm][fn][2] + bvv, v3 = acc[fm][fn][3] + bvv;
      if constexpr (Cfg<MODE>::RELU) {
        v0 = fmaxf(v0, 0.f); v1 = fmaxf(v1, 0.f); v2 = fmaxf(v2, 0.f); v3 = fmaxf(v3, 0.f);
      }
      if constexpr (MODE == M_POSTVQ) {
        *(uint2*)(outu + (((size_t)(nn*256 + oc)) << 12) + hwq) = pack4(v0,v1,v2,v3);
      } else if constexpr (MODE == M_DECONV1) {
        u16* ob = outu + (((size_t)(nn*4 + par)) << 19) + (size_t)hwq * 128 + oc;
        ob[0]   = f2bf(v0);
        ob[128] = f2bf(v1);
        ob[256] = f2bf(v2);
        ob[384] = f2bf(v3);
      } else { // M_DECONV2 -> x_recon fp32
        if (lr < 3) {
          const int hq = (pq >> 7) & 127, wq = pq & 127;
          const int qy = par >> 1, qx = par & 1;
          const int oh = 2*hq + qy;
          float* ob = outf + (((size_t)(nn*3 + oc)) << 16) + (oh << 8) + qx;
          ob[2*wq]     = v0;
          ob[2*wq + 2] = v1;
          ob[2*wq + 4] = v2;
          ob[2*wq + 6] = v3;
        }
      }
    }
  }
}

// ===========================================================================
// Weight preps
// ===========================================================================
__global__ void prep_enc(const float* __restrict__ ew1, const float* __restrict__ ew2,
                         const float* __restrict__ pvw, const float* __restrict__ emb,
                         float* bt1, u16* bt2h, u16* bt2l, float* btp,
                         float* Et, float* enrm) {
  int i = blockIdx.x * 256 + threadIdx.x;
  if (i < 6144) {                               // bt1 [k=ic*16+r][128]
    int k = i >> 7, oc = i & 127;
    bt1[i] = ew1[oc*48 + k];
  } else if ((i -= 6144) < 524288) {            // bt2h/l [oc][k=tap*128+ic] bf16
    int oc = i >> 11, k = i & 2047;
    int r = k >> 7, ic = k & 127;
    float v = ew2[oc*2048 + ic*16 + r];
    u16 hi = f2bf(v);
    bt2h[i] = hi;
    bt2l[i] = f2bf(v - bf2f(hi));
  } else if ((i -= 524288) < 16384) {           // btp [k][64]
    int k = i >> 6, oc = i & 63;
    btp[i] = pvw[oc*256 + k];
  } else if ((i -= 16384) < 32768) {            // Et [d][code] fp32
    int d = i >> 9, code = i & 511;
    Et[i] = emb[code*64 + d];
  } else if ((i -= 32768) < 512) {              // ||e||^2 fp32
    float s = 0.f;
    const float* er = emb + (size_t)i * 64;
    #pragma unroll
    for (int d = 0; d < 64; ++d) s += er[d]*er[d];
    enrm[i] = s;
  }
}

__global__ void prep_dec(const float* __restrict__ qvw, const float* __restrict__ dw1,
                         const float* __restrict__ dw2,
                         u16* btq, u16* btd, u16* btd2) {
  int i = blockIdx.x * 256 + threadIdx.x;
  if (i < 147456) {                             // btq [oc][k=r*64+ic]
    int oc = i / 576, rem = i - oc*576, r = rem >> 6, ic = rem & 63;
    btq[i] = f2bf(qvw[oc*576 + ic*9 + r]);
  } else if ((i -= 147456) < 524288) {          // btd [par][oc][k=j*256+ic]
    int pr = i >> 17, oc = (i >> 10) & 127, j = (i >> 8) & 3, ic = i & 255;
    int py = pr >> 1, px = pr & 1, j1 = j >> 1, j0 = j & 1;
    btd[i] = f2bf(dw1[oc*4096 + ic*16 + (py + 2*j1)*4 + (px + 2*j0)]);
  } else if ((i -= 524288) < 32768) {           // btd2 [q][oc16][k=tap*128+ic]
    int q = i >> 13, oc = (i >> 9) & 15, tap = (i >> 7) & 3, ic = i & 127;
    int qy = q >> 1, qx = q & 1, j1 = tap >> 1, j0 = tap & 1;
    btd2[i] = (oc < 3) ? f2bf(dw2[oc*2048 + ic*16 + (qy + 2*j1)*4 + (qx + 2*j0)]) : (u16)0;
  }
}

// ===========================================================================
// VQ argmin: fp32 register-tiled GEMM (dist = ||e||^2 - 2 z.e), 64 px/block,
// 4px x 8code register tile per thread, LDS-staged Z tile + E^T chunks.
// ===========================================================================
__global__ __launch_bounds__(256, 2) void vq_argmin_f32(const float* __restrict__ ze,
                                                        const float* __restrict__ Et,
                                                        const float* __restrict__ enrm,
                                                        int* __restrict__ idxbuf) {
  __shared__ __align__(16) float Zs[64*68];    // [d][px] pad 68
  __shared__ __align__(16) float Es[32*132];   // [kk][code] pad 132
  __shared__ float nrmS[128];
  __shared__ float redv[64*17];
  __shared__ int   redi[64*17];

  const int t = threadIdx.x;
  const int base = blockIdx.x * 64;
  const int n = base >> 12, hwb = base & 4095;
  const int pxl = t & 63, wv = t >> 6;

  // stage Z tile (coalesced per d)
  const float* zb = ze + (((size_t)n << 6) << 12) + hwb + pxl;
  #pragma unroll
  for (int i = 0; i < 16; ++i) {
    int d = i*4 + wv;
    Zs[d*68 + pxl] = zb[(size_t)d << 12];
  }

  const int ti = t & 15, tj = t >> 4;

  float bv[4]; int bi[4];
  #pragma unroll
  for (int i = 0; i < 4; ++i) { bv[i] = 3.402823466e38f; bi[i] = 0; }

  for (int c = 0; c < 4; ++c) {
    float acc[4][8];
    #pragma unroll
    for (int i = 0; i < 4; ++i)
      #pragma unroll
      for (int j = 0; j < 8; ++j) acc[i][j] = 0.f;

    for (int hh = 0; hh < 2; ++hh) {
      __syncthreads();
      #pragma unroll
      for (int i = 0; i < 4; ++i) {
        int fid = i*256 + t, row = fid >> 5, c4 = fid & 31;
        *(float4*)&Es[row*132 + c4*4] =
            *(const float4*)(Et + (size_t)(hh*32 + row)*512 + c*128 + c4*4);
      }
      if (hh == 0 && t < 128) nrmS[t] = enrm[c*128 + t];
      __syncthreads();
      #pragma unroll 4
      for (int kk = 0; kk < 32; ++kk) {
        float4 a0 = *(const float4*)&Zs[(hh*32 + kk)*68 + ti*4];
        float4 b0 = *(const float4*)&Es[kk*132 + tj*8];
        float4 b1 = *(const float4*)&Es[kk*132 + tj*8 + 4];
        float a[4] = {a0.x, a0.y, a0.z, a0.w};
        float b[8] = {b0.x,b0.y,b0.z,b0.w, b1.x,b1.y,b1.z,b1.w};
        #pragma unroll
        for (int i = 0; i < 4; ++i)
          #pragma unroll
          for (int j = 0; j < 8; ++j)
            acc[i][j] += a[i]*b[j];
      }
    }
    #pragma unroll
    for (int j = 0; j < 8; ++j) {
      int code = c*128 + tj*8 + j;
      float nv = nrmS[tj*8 + j];
      #pragma unroll
      for (int i = 0; i < 4; ++i) {
        float d = nv - 2.f*acc[i][j];
        if (d < bv[i]) { bv[i] = d; bi[i] = code; }
      }
    }
  }

  #pragma unroll
  for (int i = 0; i < 4; ++i) {
    redv[(ti*4 + i)*17 + tj] = bv[i];
    redi[(ti*4 + i)*17 + tj] = bi[i];
  }
  __syncthreads();
  if (t < 64) {
    float best = 3.402823466e38f; int bid = 0x7fffffff;
    #pragma unroll
    for (int j = 0; j < 16; ++j) {
      float v = redv[t*17 + j]; int ix = redi[t*17 + j];
      if (v < best || (v == best && ix < bid)) { best = v; bid = ix; }
    }
    idxbuf[base + t] = bid;
  }
}

// ===========================================================================
// Quantize + loss + histogram (exact fp32 z/e; bf16 qz for decoder)
// ===========================================================================
__global__ void vq_quant(const float* __restrict__ ze, const float* __restrict__ emb,
                         const int* __restrict__ idxbuf, u16* __restrict__ qz,
                         int* __restrict__ hist, float* __restrict__ loss_sum) {
  const int t = threadIdx.x;
  const int p = blockIdx.x * 256 + t;
  const int n = p >> 12, hw = p & 4095;
  const int ix = idxbuf[p];
  const float* er = emb + (size_t)ix * 64;
  const float* zb = ze + ((size_t)n << 18) + hw;
  u16* qb = qz + ((size_t)n << 18) + hw;
  float ls = 0.f;
  #pragma unroll
  for (int d = 0; d < 64; ++d) {
    float e = er[d];
    float z = zb[(size_t)d << 12];
    qb[(size_t)d << 12] = f2bf(e);
    float df = e - z; ls += df*df;
  }
  atomicAdd(&hist[ix], 1);
  #pragma unroll
  for (int o = 32; o; o >>= 1) ls += __shfl_down(ls, o, 64);
  if ((t & 63) == 0) atomicAdd(loss_sum, ls);
}

__global__ void finalize_kernel(const int* __restrict__ hist,
                                const float* __restrict__ loss_sum,
                                float* __restrict__ out_loss,
                                float* __restrict__ out_perp) {
  __shared__ float red[512];
  int t = threadIdx.x;
  float pr = (float)hist[t] * (1.f/32768.f);
  red[t] = pr * logf(pr + 1e-10f);
  __syncthreads();
  for (int s = 256; s; s >>= 1) {
    if (t < s) red[t] += red[t + s];
    __syncthreads();
  }
  if (t == 0) {
    out_loss[0] = 1.25f * loss_sum[0] * (1.f/2097152.f);
    out_perp[0] = expf(-red[0]);
  }
}

// ===========================================================================
extern "C" void kernel_launch(void* const* d_in, const int* in_sizes, int n_in,
                              void* d_out, int out_size, void* d_ws, size_t ws_size,
                              hipStream_t stream) {
  (void)in_sizes; (void)n_in; (void)ws_size;
  const float* x   = (const float*)d_in[0];
  const float* ew1 = (const float*)d_in[1];
  const float* eb1 = (const float*)d_in[2];
  const float* ew2 = (const float*)d_in[3];
  const float* eb2 = (const float*)d_in[4];
  const float* pvw = (const float*)d_in[5];
  const float* pvb = (const float*)d_in[6];
  const float* emb = (const float*)d_in[7];
  const float* qvw = (const float*)d_in[8];
  const float* qvb = (const float*)d_in[9];
  const float* dw1 = (const float*)d_in[10];
  const float* db1 = (const float*)d_in[11];
  const float* dw2 = (const float*)d_in[12];
  const float* db2 = (const float*)d_in[13];
  float* out = (float*)d_out;

  char* ws = (char*)d_ws;
  float* h1   = (float*)(ws);                    // [8,128,128,128] f32, 67108864 B
  float* h2   = (float*)(ws + 67108864);         // [8,256,64,64] f32, 33554432 B
  float* ze   = (float*)(ws + 100663296);        // [8,64,64,64] f32, 8388608 B
  u16*   qz   = (u16*)  (ws + 109051904);        // [8,64,64,64] bf16, 4194304 B
  int*   hist = (int*)  (ws + 113246208);        // 2048 B
  float* lsum = (float*)(ws + 113248256);        // 64 B
  float* bt1  = (float*)(ws + 113248320);        // 24576 B
  float* btp  = (float*)(ws + 113272896);        // 65536 B
  u16*   bt2h = (u16*)  (ws + 113338432);        // 1048576 B
  u16*   bt2l = (u16*)  (ws + 114387008);        // 1048576 B
  u16*   btq  = (u16*)  (ws + 115435584);        // 294912 B
  u16*   btd  = (u16*)  (ws + 115730496);        // 1048576 B
  u16*   btd2 = (u16*)  (ws + 116779072);        // 65536 B
  float* Et   = (float*)(ws + 116844608);        // 131072 B
  float* enrm = (float*)(ws + 116975680);        // 2048 B
  int*   idxb = (int*)  (ws + 116977728);        // 131072 B
  u16* g  = (u16*)(ws + 67108864);  // bf16 postvq out, overlays h2 (dead)
  u16* g2 = (u16*)ws;               // bf16 deconv1 out, overlays h1 (dead)

  hipMemsetAsync(hist, 0, 2048 + 64, stream);
  prep_enc<<<2266, 256, 0, stream>>>(ew1, ew2, pvw, emb, bt1, bt2h, bt2l, btp, Et, enrm);
  prep_dec<<<2752, 256, 0, stream>>>(qvw, dw1, dw2, btq, btd, btd2);

  conv_f32<F_CONV1><<<1024, 256, 0, stream>>>(x,  bt1, eb1, h1);
  conv2_mfma3<<<512, 256, 0, stream>>>(h1, bt2h, bt2l, eb2, h2);
  conv_f32<F_PREVQ><<<512,  256, 0, stream>>>(h2, btp, pvb, ze);

  vq_argmin_f32<<<512, 256, 0, stream>>>(ze, Et, enrm, idxb);
  vq_quant<<<128, 256, 0, stream>>>(ze, emb, idxb, qz, hist, lsum);
  finalize_kernel<<<1, 512, 0, stream>>>(hist, lsum, out, out + (out_size - 1));

  conv_mfma<M_POSTVQ> <<<512, 256, 0, stream>>>(qz, btq, qvb, g);
  conv_mfma<M_DECONV1><<<dim3(256, 4), 256, 0, stream>>>(g, btd, db1, g2);
  conv_mfma<M_DECONV2><<<dim3(1024, 4), 256, 0, stream>>>(g2, btd2, db2, out + 1);
}

// Round 6
// 509.537 us; speedup vs baseline: 3.3851x; 1.1243x over previous
//
#include <hip/hip_runtime.h>
#include <math.h>

typedef unsigned short u16;
typedef unsigned int uint;
typedef __attribute__((ext_vector_type(8))) short bh8;   // 8 bf16 in 4 VGPRs
typedef __attribute__((ext_vector_type(4))) float f32x4;

#define DEV __device__ __forceinline__

DEV u16 f2bf(float x) {                       // fp32 -> bf16 RNE
  uint u = __builtin_bit_cast(uint, x);
  return (u16)((u + 0x7FFFu + ((u >> 16) & 1u)) >> 16);
}
DEV float bf2f(u16 h) { return __builtin_bit_cast(float, (uint)h << 16); }

// Bijective XCD-aware swizzle: 8 XCDs, contiguous chunk per XCD.
// Requires gridDim.x % 8 == 0 (all our grids: 512/1024/4096).
DEV int xcd_swz(int bid, int nb) {
  int c = nb >> 3;
  return (bid & 7) * c + (bid >> 3);
}

union Pack { u16 u[8]; uint4 v; };

DEV uint2 pack4(float v0, float v1, float v2, float v3) {
  uint2 s;
  s.x = (uint)f2bf(v0) | ((uint)f2bf(v1) << 16);
  s.y = (uint)f2bf(v2) | ((uint)f2bf(v3) << 16);
  return s;
}

// ===========================================================================
// ENCODER stage 1/3: fp32 VALU implicit-GEMM (conv1, prevq — exact numerics).
// ===========================================================================
enum { F_CONV1, F_PREVQ };

template<int MODE> struct FCfg;
template<> struct FCfg<F_CONV1> { static constexpr int K=48,  BM=128, BN=128, NOC=128, RELU=1; };
template<> struct FCfg<F_PREVQ> { static constexpr int K=256, BM=64,  BN=64,  NOC=64,  RELU=0; };

template<int MODE>
DEV float gatherF(const float* __restrict__ src, int n, int h, int w, int k) {
  if constexpr (MODE == F_CONV1) {            // k = ic*16 + r
    int ic = k >> 4, r = k & 15;
    int ih = 2*h - 1 + (r >> 2), iw = 2*w - 1 + (r & 3);
    return ((unsigned)ih < 256u && (unsigned)iw < 256u)
      ? src[((n*3 + ic) << 16) + (ih << 8) + iw] : 0.f;
  } else {                                    // PREVQ: k = ic
    return src[((n*256 + k) << 12) + (h << 6) + w];
  }
}

template<int MODE>
__global__ __launch_bounds__(256, 4) void conv_f32(const float* __restrict__ src,
                                                   const float* __restrict__ Bt,
                                                   const float* __restrict__ bias,
                                                   float* __restrict__ out) {
  constexpr int K  = FCfg<MODE>::K,  BM = FCfg<MODE>::BM;
  constexpr int BN = FCfg<MODE>::BN, NOC = FCfg<MODE>::NOC;
  constexpr int NT = NOC / BN;
  constexpr int MH = BM / 64, NH = BN / 64;
  constexpr int AE = 16*BM/256, KS = 256/BM;

  __shared__ __align__(16) float As[16*BM];
  __shared__ __align__(16) float Bs[16*BN];

  const int t = threadIdx.x;
  const int nt = (NT > 1) ? (int)(blockIdx.x % NT) : 0;
  const int mt = (NT > 1) ? (int)(blockIdx.x / NT) : (int)blockIdx.x;

  const int pl = t & (BM-1), kb = t / BM;
  const int p = mt*BM + pl;
  int n, h, w;
  if constexpr (MODE == F_CONV1) { n = p >> 14; h = (p >> 7) & 127; w = p & 127; }
  else                           { n = p >> 12; h = (p >> 6) & 63;  w = p & 63;  }

  const int ti = t & 15, tj = t >> 4;

  float acc[MH*4][NH*4];
  #pragma unroll
  for (int i = 0; i < MH*4; ++i)
    #pragma unroll
    for (int j = 0; j < NH*4; ++j) acc[i][j] = 0.f;

  for (int k0 = 0; k0 < K; k0 += 16) {
    #pragma unroll
    for (int jj = 0; jj < AE; ++jj) {
      int kr = jj*KS + kb;
      As[kr*BM + pl] = gatherF<MODE>(src, n, h, w, k0 + kr);
    }
    #pragma unroll
    for (int jj = 0; jj < (16*BN/4)/256; ++jj) {
      int id = jj*256 + t;
      int kr = id / (BN/4), c4 = id % (BN/4);
      ((float4*)Bs)[kr*(BN/4) + c4] =
          *((const float4*)(Bt + (size_t)(k0 + kr)*NOC + nt*BN) + c4);
    }
    __syncthreads();
    #pragma unroll
    for (int kk = 0; kk < 16; ++kk) {
      float a[MH*4], b[NH*4];
      *(float4*)&a[0] = *(const float4*)&As[kk*BM + ti*4];
      if constexpr (MH == 2) *(float4*)&a[4] = *(const float4*)&As[kk*BM + 64 + ti*4];
      *(float4*)&b[0] = *(const float4*)&Bs[kk*BN + tj*4];
      if constexpr (NH == 2) *(float4*)&b[4] = *(const float4*)&Bs[kk*BN + 64 + tj*4];
      #pragma unroll
      for (int i = 0; i < MH*4; ++i)
        #pragma unroll
        for (int j = 0; j < NH*4; ++j)
          acc[i][j] += a[i]*b[j];
    }
    __syncthreads();
  }

  #pragma unroll
  for (int i = 0; i < MH*4; ++i) {
    int pp = mt*BM + (i>>2)*64 + ti*4 + (i&3);
    int nn, hh, ww;
    if constexpr (MODE == F_CONV1) { nn = pp >> 14; hh = (pp >> 7) & 127; ww = pp & 127; }
    else                           { nn = pp >> 12; hh = (pp >> 6) & 63;  ww = pp & 63;  }
    #pragma unroll
    for (int j = 0; j < NH*4; ++j) {
      int oc = nt*BN + (j>>2)*64 + tj*4 + (j&3);
      float v = acc[i][j] + bias[oc];
      if constexpr (FCfg<MODE>::RELU) v = fmaxf(v, 0.f);
      if constexpr (MODE == F_CONV1)
        out[((nn*128 + oc) << 14) + (hh << 7) + ww] = v;
      else
        out[((nn*64 + oc) << 12) + (hh << 6) + ww] = v;
    }
  }
}

// ===========================================================================
// ENCODER stage 2/3: conv2 via bf16x3 split-precision MFMA (fp32-accurate).
// XCD-swizzled grid: nt inner, mt outer -> one XCD chunk = one image.
// ===========================================================================
__global__ __launch_bounds__(256, 2) void conv2_mfma3(const float* __restrict__ src,
                                                      const u16* __restrict__ Bh,
                                                      const u16* __restrict__ Bl,
                                                      const float* __restrict__ bias,
                                                      float* __restrict__ out) {
  __shared__ u16 Ah[128*72], Al[128*72], Bhs[128*72], Bls[128*72];

  const int t = threadIdx.x;
  const int bid = xcd_swz((int)blockIdx.x, (int)gridDim.x);
  const int nt = bid & 1, mt = bid >> 1;
  const int pl = t & 127, kb = t >> 7;
  const int p = mt*128 + pl;
  const int n = p >> 12, h = (p >> 6) & 63, w = p & 63;
  const int lane = t & 63, wv = t >> 6;
  const int lr = lane & 15, lg = lane >> 4;
  const int wm = wv & 1, wn = wv >> 1;

  f32x4 acc[4][4];
  #pragma unroll
  for (int fm = 0; fm < 4; ++fm)
    #pragma unroll
    for (int fn = 0; fn < 4; ++fn)
      #pragma unroll
      for (int q = 0; q < 4; ++q) acc[fm][fn][q] = 0.f;

  for (int k0 = 0; k0 < 2048; k0 += 64) {
    __syncthreads();
    const int r = k0 >> 7, icb = (k0 & 127) + kb*32;
    const int ih = 2*h - 1 + (r >> 2), iw = 2*w - 1 + (r & 3);
    const bool ok = ((unsigned)ih < 128u) && ((unsigned)iw < 128u);
    const float* sb = src + ((size_t)((n*128 + icb)) << 14) + (ih << 7) + iw;
    Pack ph[4], pl4[4];
    #pragma unroll
    for (int jj = 0; jj < 32; ++jj) {
      float v = ok ? sb[(size_t)jj << 14] : 0.f;
      u16 hi = f2bf(v);
      u16 lo = f2bf(v - bf2f(hi));
      ph[jj >> 3].u[jj & 7]  = hi;
      pl4[jj >> 3].u[jj & 7] = lo;
    }
    #pragma unroll
    for (int i = 0; i < 4; ++i) {
      *(uint4*)&Ah[pl*72 + kb*32 + i*8] = ph[i].v;
      *(uint4*)&Al[pl*72 + kb*32 + i*8] = pl4[i].v;
    }
    #pragma unroll
    for (int i = 0; i < 4; ++i) {
      int id = i*256 + t, oc = id >> 3, ch = id & 7;
      size_t bo = (size_t)(nt*128 + oc)*2048 + k0 + ch*8;
      *(uint4*)&Bhs[oc*72 + ch*8] = *(const uint4*)(Bh + bo);
      *(uint4*)&Bls[oc*72 + ch*8] = *(const uint4*)(Bl + bo);
    }
    __syncthreads();
    #pragma unroll
    for (int ks = 0; ks < 2; ++ks) {
      bh8 afh[4], afl[4];
      #pragma unroll
      for (int fm = 0; fm < 4; ++fm) {
        afh[fm] = *(const bh8*)&Ah[(wm*64 + fm*16 + lr)*72 + ks*32 + lg*8];
        afl[fm] = *(const bh8*)&Al[(wm*64 + fm*16 + lr)*72 + ks*32 + lg*8];
      }
      #pragma unroll
      for (int fn = 0; fn < 4; ++fn) {
        bh8 bfh = *(const bh8*)&Bhs[(wn*64 + fn*16 + lr)*72 + ks*32 + lg*8];
        bh8 bfl = *(const bh8*)&Bls[(wn*64 + fn*16 + lr)*72 + ks*32 + lg*8];
        #pragma unroll
        for (int fm = 0; fm < 4; ++fm) {
          acc[fm][fn] = __builtin_amdgcn_mfma_f32_16x16x32_bf16(afh[fm], bfh, acc[fm][fn], 0,0,0);
          acc[fm][fn] = __builtin_amdgcn_mfma_f32_16x16x32_bf16(afl[fm], bfh, acc[fm][fn], 0,0,0);
          acc[fm][fn] = __builtin_amdgcn_mfma_f32_16x16x32_bf16(afh[fm], bfl, acc[fm][fn], 0,0,0);
        }
      }
    }
  }

  #pragma unroll
  for (int fm = 0; fm < 4; ++fm) {
    const int pq = mt*128 + wm*64 + fm*16 + lg*4;
    const int nn = pq >> 12, hwq = pq & 4095;
    #pragma unroll
    for (int fn = 0; fn < 4; ++fn) {
      const int oc = nt*128 + wn*64 + fn*16 + lr;
      const float bv = bias[oc];
      float v0 = fmaxf(acc[fm][fn][0] + bv, 0.f);
      float v1 = fmaxf(acc[fm][fn][1] + bv, 0.f);
      float v2 = fmaxf(acc[fm][fn][2] + bv, 0.f);
      float v3 = fmaxf(acc[fm][fn][3] + bv, 0.f);
      *(float4*)(out + (((size_t)(nn*256 + oc)) << 12) + hwq) = make_float4(v0,v1,v2,v3);
    }
  }
}

// ===========================================================================
// DECODER: bf16 MFMA implicit-GEMM. 1D XCD-swizzled grids, par innermost.
// ===========================================================================
enum { M_POSTVQ, M_DECONV1, M_DECONV2 };

template<int MODE> struct Cfg;
template<> struct Cfg<M_POSTVQ> { static constexpr int K=576,  BN=128, NOC=256, RELU=0; };
template<> struct Cfg<M_DECONV1>{ static constexpr int K=1024, BN=128, NOC=128, RELU=1; };
template<> struct Cfg<M_DECONV2>{ static constexpr int K=512,  BN=16,  NOC=16,  RELU=0; };

template<int MODE>
__global__ __launch_bounds__(256, 2) void conv_mfma(const void* __restrict__ src_,
                                                    const u16* __restrict__ Bt,
                                                    const float* __restrict__ bias,
                                                    void* __restrict__ out_) {
  constexpr int K  = Cfg<MODE>::K;
  constexpr int BN = Cfg<MODE>::BN;
  constexpr int NOC = Cfg<MODE>::NOC;
  constexpr int NT = NOC / BN;
  constexpr int WM = (BN == 128) ? 2 : 4;
  constexpr int WN = (BN == 128) ? 2 : 1;
  constexpr int FM = 128 / WM / 16;
  constexpr int FN = BN / WN / 16;

  __shared__ u16 As[128 * 72];
  __shared__ u16 Bs[BN * 72];

  const int t = threadIdx.x;
  int bid = xcd_swz((int)blockIdx.x, (int)gridDim.x);
  int par = 0;
  if constexpr (MODE == M_DECONV1 || MODE == M_DECONV2) {
    par = bid & 3;             // parity innermost -> same-image parities share XCD L2
    bid >>= 2;
    Bt += (size_t)par * NOC * K;
  }
  const int nt = (NT > 1) ? (bid % NT) : 0;
  const int mt = (NT > 1) ? (bid / NT) : bid;

  const int pl = t & 127, kb = t >> 7;
  const int p = mt * 128 + pl;
  int n, h, w;
  if constexpr (MODE == M_DECONV2) { n = p >> 14; h = (p >> 7) & 127; w = p & 127; }
  else                             { n = p >> 12; h = (p >> 6) & 63;  w = p & 63;  }

  const int lane = t & 63, wv = t >> 6;
  const int lr = lane & 15, lg = lane >> 4;
  const int wm = (WM == 2) ? (wv & 1) : wv;
  const int wn = (WM == 2) ? (wv >> 1) : 0;

  f32x4 acc[FM][FN];
  #pragma unroll
  for (int fm = 0; fm < FM; ++fm)
    #pragma unroll
    for (int fn = 0; fn < FN; ++fn)
      #pragma unroll
      for (int q = 0; q < 4; ++q) acc[fm][fn][q] = 0.f;

  const u16* srcu = (const u16*)src_;

  for (int k0 = 0; k0 < K; k0 += 64) {
    __syncthreads();
    Pack pk[4];
    if constexpr (MODE == M_DECONV2) {
      int tap = k0 >> 7, icb = k0 & 127;
      int j1 = tap >> 1, j0 = tap & 1;
      int qy = par >> 1, qx = par & 1;
      int ih = h - 1 + qy + j1, iw = w - 1 + qx + j0;
      bool ok = ((unsigned)ih < 128u) && ((unsigned)iw < 128u);
      int ipar = ((ih & 1) << 1) | (iw & 1);
      const u16* sb = srcu + ((((size_t)(n*4 + ipar)) << 12) + ((ih >> 1) << 6) + (iw >> 1)) * 128
                          + icb + kb * 32;
      #pragma unroll
      for (int i = 0; i < 4; ++i)
        pk[i].v = ok ? *(const uint4*)(sb + i*8) : make_uint4(0,0,0,0);
    } else {
      const u16* sb; bool ok = true;
      if constexpr (MODE == M_POSTVQ) {
        int r = k0 >> 6, kh = r / 3, kw = r - 3*kh;
        int ih = h - 1 + kh, iw = w - 1 + kw;
        ok = ((unsigned)ih < 64u) && ((unsigned)iw < 64u);
        sb = srcu + (size_t)(((n << 6) + kb*32) << 12) + (ih << 6) + iw;
      } else { // M_DECONV1
        int j = k0 >> 8, icb = k0 & 255;
        int j1 = j >> 1, j0 = j & 1;
        int py = par >> 1, px = par & 1;
        int ih = h + py - 1 + j1, iw = w + px - 1 + j0;
        ok = ((unsigned)ih < 64u) && ((unsigned)iw < 64u);
        sb = srcu + (size_t)((n*256 + icb + kb*32) << 12) + (ih << 6) + iw;
      }
      #pragma unroll
      for (int jj = 0; jj < 32; ++jj) {
        u16 v = ok ? sb[(size_t)jj * 4096] : (u16)0;
        pk[jj >> 3].u[jj & 7] = v;
      }
    }
    #pragma unroll
    for (int i = 0; i < 4; ++i)
      *(uint4*)&As[pl*72 + kb*32 + i*8] = pk[i].v;

    constexpr int NBI = (BN*8 + 255) / 256;
    #pragma unroll
    for (int i = 0; i < NBI; ++i) {
      int id = i*256 + t;
      bool okb = true;
      if constexpr ((BN*8) % 256 != 0) okb = (id < BN*8);
      if (okb) {
        int oc = id >> 3, ch = id & 7;
        *(uint4*)&Bs[oc*72 + ch*8] = *(const uint4*)(Bt + (size_t)oc*K + k0 + ch*8);
      }
    }
    __syncthreads();

    #pragma unroll
    for (int ks = 0; ks < 2; ++ks) {
      bh8 af[FM];
      #pragma unroll
      for (int fm = 0; fm < FM; ++fm)
        af[fm] = *(const bh8*)&As[(wm*(128/WM) + fm*16 + lr)*72 + ks*32 + lg*8];
      #pragma unroll
      for (int fn = 0; fn < FN; ++fn) {
        bh8 bf = *(const bh8*)&Bs[(wn*(BN/WN) + fn*16 + lr)*72 + ks*32 + lg*8];
        #pragma unroll
        for (int fm = 0; fm < FM; ++fm)
          acc[fm][fn] = __builtin_amdgcn_mfma_f32_16x16x32_bf16(af[fm], bf, acc[fm][fn], 0, 0, 0);
      }
    }
  }

  u16*   outu = (u16*)out_;
  float* outf = (float*)out_;
  #pragma unroll
  for (int fm = 0; fm < FM; ++fm) {
    const int pq = mt*128 + wm*(128/WM) + fm*16 + lg*4;
    int nn, hwq;
    if constexpr (MODE == M_DECONV2) { nn = pq >> 14; hwq = pq & 16383; }
    else                             { nn = pq >> 12; hwq = pq & 4095;  }
    #pragma unroll
    for (int fn = 0; fn < FN; ++fn) {
      const int oc = nt*BN + wn*(BN/WN) + fn*16 + lr;
      float bvv;
      if constexpr (MODE == M_DECONV2) bvv = (lr < 3) ? bias[oc] : 0.f;
      else                             bvv = bias[oc];
      float v0 = acc[fm][fn][0] + bvv, v1 = acc[fm][fn][1] + bvv;
      float v2 = acc[fm][fn][2] + bvv, v3 = acc[fm][fn][3] + bvv;
      if constexpr (Cfg<MODE>::RELU) {
        v0 = fmaxf(v0, 0.f); v1 = fmaxf(v1, 0.f); v2 = fmaxf(v2, 0.f); v3 = fmaxf(v3, 0.f);
      }
      if constexpr (MODE == M_POSTVQ) {
        *(uint2*)(outu + (((size_t)(nn*256 + oc)) << 12) + hwq) = pack4(v0,v1,v2,v3);
      } else if constexpr (MODE == M_DECONV1) {
        u16* ob = outu + (((size_t)(nn*4 + par)) << 19) + (size_t)hwq * 128 + oc;
        ob[0]   = f2bf(v0);
        ob[128] = f2bf(v1);
        ob[256] = f2bf(v2);
        ob[384] = f2bf(v3);
      } else { // M_DECONV2 -> x_recon fp32
        if (lr < 3) {
          const int hq = (pq >> 7) & 127, wq = pq & 127;
          const int qy = par >> 1, qx = par & 1;
          const int oh = 2*hq + qy;
          float* ob = outf + (((size_t)(nn*3 + oc)) << 16) + (oh << 8) + qx;
          ob[2*wq]     = v0;
          ob[2*wq + 2] = v1;
          ob[2*wq + 4] = v2;
          ob[2*wq + 6] = v3;
        }
      }
    }
  }
}

// ===========================================================================
// Weight preps
// ===========================================================================
__global__ void prep_enc(const float* __restrict__ ew1, const float* __restrict__ ew2,
                         const float* __restrict__ pvw, const float* __restrict__ emb,
                         float* bt1, u16* bt2h, u16* bt2l, float* btp,
                         float* Et, float* enrm) {
  int i = blockIdx.x * 256 + threadIdx.x;
  if (i < 6144) {                               // bt1 [k=ic*16+r][128]
    int k = i >> 7, oc = i & 127;
    bt1[i] = ew1[oc*48 + k];
  } else if ((i -= 6144) < 524288) {            // bt2h/l [oc][k=tap*128+ic] bf16
    int oc = i >> 11, k = i & 2047;
    int r = k >> 7, ic = k & 127;
    float v = ew2[oc*2048 + ic*16 + r];
    u16 hi = f2bf(v);
    bt2h[i] = hi;
    bt2l[i] = f2bf(v - bf2f(hi));
  } else if ((i -= 524288) < 16384) {           // btp [k][64]
    int k = i >> 6, oc = i & 63;
    btp[i] = pvw[oc*256 + k];
  } else if ((i -= 16384) < 32768) {            // Et [d][code] fp32
    int d = i >> 9, code = i & 511;
    Et[i] = emb[code*64 + d];
  } else if ((i -= 32768) < 512) {              // ||e||^2 fp32
    float s = 0.f;
    const float* er = emb + (size_t)i * 64;
    #pragma unroll
    for (int d = 0; d < 64; ++d) s += er[d]*er[d];
    enrm[i] = s;
  }
}

__global__ void prep_dec(const float* __restrict__ qvw, const float* __restrict__ dw1,
                         const float* __restrict__ dw2,
                         u16* btq, u16* btd, u16* btd2) {
  int i = blockIdx.x * 256 + threadIdx.x;
  if (i < 147456) {                             // btq [oc][k=r*64+ic]
    int oc = i / 576, rem = i - oc*576, r = rem >> 6, ic = rem & 63;
    btq[i] = f2bf(qvw[oc*576 + ic*9 + r]);
  } else if ((i -= 147456) < 524288) {          // btd [par][oc][k=j*256+ic]
    int pr = i >> 17, oc = (i >> 10) & 127, j = (i >> 8) & 3, ic = i & 255;
    int py = pr >> 1, px = pr & 1, j1 = j >> 1, j0 = j & 1;
    btd[i] = f2bf(dw1[oc*4096 + ic*16 + (py + 2*j1)*4 + (px + 2*j0)]);
  } else if ((i -= 524288) < 32768) {           // btd2 [q][oc16][k=tap*128+ic]
    int q = i >> 13, oc = (i >> 9) & 15, tap = (i >> 7) & 3, ic = i & 127;
    int qy = q >> 1, qx = q & 1, j1 = tap >> 1, j0 = tap & 1;
    btd2[i] = (oc < 3) ? f2bf(dw2[oc*2048 + ic*16 + (qy + 2*j1)*4 + (qx + 2*j0)]) : (u16)0;
  }
}

// ===========================================================================
// VQ argmin: fp32 register-tiled GEMM (dist = ||e||^2 - 2 z.e), 64 px/block,
// 4px x 8code register tile per thread, LDS-staged Z tile + E^T chunks.
// ===========================================================================
__global__ __launch_bounds__(256, 2) void vq_argmin_f32(const float* __restrict__ ze,
                                                        const float* __restrict__ Et,
                                                        const float* __restrict__ enrm,
                                                        int* __restrict__ idxbuf) {
  __shared__ __align__(16) float Zs[64*68];    // [d][px] pad 68
  __shared__ __align__(16) float Es[32*132];   // [kk][code] pad 132
  __shared__ float nrmS[128];
  __shared__ float redv[64*17];
  __shared__ int   redi[64*17];

  const int t = threadIdx.x;
  const int base = blockIdx.x * 64;
  const int n = base >> 12, hwb = base & 4095;
  const int pxl = t & 63, wv = t >> 6;

  const float* zb = ze + (((size_t)n << 6) << 12) + hwb + pxl;
  #pragma unroll
  for (int i = 0; i < 16; ++i) {
    int d = i*4 + wv;
    Zs[d*68 + pxl] = zb[(size_t)d << 12];
  }

  const int ti = t & 15, tj = t >> 4;

  float bv[4]; int bi[4];
  #pragma unroll
  for (int i = 0; i < 4; ++i) { bv[i] = 3.402823466e38f; bi[i] = 0; }

  for (int c = 0; c < 4; ++c) {
    float acc[4][8];
    #pragma unroll
    for (int i = 0; i < 4; ++i)
      #pragma unroll
      for (int j = 0; j < 8; ++j) acc[i][j] = 0.f;

    for (int hh = 0; hh < 2; ++hh) {
      __syncthreads();
      #pragma unroll
      for (int i = 0; i < 4; ++i) {
        int fid = i*256 + t, row = fid >> 5, c4 = fid & 31;
        *(float4*)&Es[row*132 + c4*4] =
            *(const float4*)(Et + (size_t)(hh*32 + row)*512 + c*128 + c4*4);
      }
      if (hh == 0 && t < 128) nrmS[t] = enrm[c*128 + t];
      __syncthreads();
      #pragma unroll 4
      for (int kk = 0; kk < 32; ++kk) {
        float4 a0 = *(const float4*)&Zs[(hh*32 + kk)*68 + ti*4];
        float4 b0 = *(const float4*)&Es[kk*132 + tj*8];
        float4 b1 = *(const float4*)&Es[kk*132 + tj*8 + 4];
        float a[4] = {a0.x, a0.y, a0.z, a0.w};
        float b[8] = {b0.x,b0.y,b0.z,b0.w, b1.x,b1.y,b1.z,b1.w};
        #pragma unroll
        for (int i = 0; i < 4; ++i)
          #pragma unroll
          for (int j = 0; j < 8; ++j)
            acc[i][j] += a[i]*b[j];
      }
    }
    #pragma unroll
    for (int j = 0; j < 8; ++j) {
      int code = c*128 + tj*8 + j;
      float nv = nrmS[tj*8 + j];
      #pragma unroll
      for (int i = 0; i < 4; ++i) {
        float d = nv - 2.f*acc[i][j];
        if (d < bv[i]) { bv[i] = d; bi[i] = code; }
      }
    }
  }

  #pragma unroll
  for (int i = 0; i < 4; ++i) {
    redv[(ti*4 + i)*17 + tj] = bv[i];
    redi[(ti*4 + i)*17 + tj] = bi[i];
  }
  __syncthreads();
  if (t < 64) {
    float best = 3.402823466e38f; int bid = 0x7fffffff;
    #pragma unroll
    for (int j = 0; j < 16; ++j) {
      float v = redv[t*17 + j]; int ix = redi[t*17 + j];
      if (v < best || (v == best && ix < bid)) { best = v; bid = ix; }
    }
    idxbuf[base + t] = bid;
  }
}

// ===========================================================================
// Quantize + loss + histogram (exact fp32 z/e; bf16 qz for decoder)
// ===========================================================================
__global__ void vq_quant(const float* __restrict__ ze, const float* __restrict__ emb,
                         const int* __restrict__ idxbuf, u16* __restrict__ qz,
                         int* __restrict__ hist, float* __restrict__ loss_sum) {
  const int t = threadIdx.x;
  const int p = blockIdx.x * 256 + t;
  const int n = p >> 12, hw = p & 4095;
  const int ix = idxbuf[p];
  const float* er = emb + (size_t)ix * 64;
  const float* zb = ze + ((size_t)n << 18) + hw;
  u16* qb = qz + ((size_t)n << 18) + hw;
  float ls = 0.f;
  #pragma unroll
  for (int d = 0; d < 64; ++d) {
    float e = er[d];
    float z = zb[(size_t)d << 12];
    qb[(size_t)d << 12] = f2bf(e);
    float df = e - z; ls += df*df;
  }
  atomicAdd(&hist[ix], 1);
  #pragma unroll
  for (int o = 32; o; o >>= 1) ls += __shfl_down(ls, o, 64);
  if ((t & 63) == 0) atomicAdd(loss_sum, ls);
}

__global__ void finalize_kernel(const int* __restrict__ hist,
                                const float* __restrict__ loss_sum,
                                float* __restrict__ out_loss,
                                float* __restrict__ out_perp) {
  __shared__ float red[512];
  int t = threadIdx.x;
  float pr = (float)hist[t] * (1.f/32768.f);
  red[t] = pr * logf(pr + 1e-10f);
  __syncthreads();
  for (int s = 256; s; s >>= 1) {
    if (t < s) red[t] += red[t + s];
    __syncthreads();
  }
  if (t == 0) {
    out_loss[0] = 1.25f * loss_sum[0] * (1.f/2097152.f);
    out_perp[0] = expf(-red[0]);
  }
}

// ===========================================================================
extern "C" void kernel_launch(void* const* d_in, const int* in_sizes, int n_in,
                              void* d_out, int out_size, void* d_ws, size_t ws_size,
                              hipStream_t stream) {
  (void)in_sizes; (void)n_in; (void)ws_size;
  const float* x   = (const float*)d_in[0];
  const float* ew1 = (const float*)d_in[1];
  const float* eb1 = (const float*)d_in[2];
  const float* ew2 = (const float*)d_in[3];
  const float* eb2 = (const float*)d_in[4];
  const float* pvw = (const float*)d_in[5];
  const float* pvb = (const float*)d_in[6];
  const float* emb = (const float*)d_in[7];
  const float* qvw = (const float*)d_in[8];
  const float* qvb = (const float*)d_in[9];
  const float* dw1 = (const float*)d_in[10];
  const float* db1 = (const float*)d_in[11];
  const float* dw2 = (const float*)d_in[12];
  const float* db2 = (const float*)d_in[13];
  float* out = (float*)d_out;

  char* ws = (char*)d_ws;
  float* h1   = (float*)(ws);                    // [8,128,128,128] f32, 67108864 B
  float* h2   = (float*)(ws + 67108864);         // [8,256,64,64] f32, 33554432 B
  float* ze   = (float*)(ws + 100663296);        // [8,64,64,64] f32, 8388608 B
  u16*   qz   = (u16*)  (ws + 109051904);        // [8,64,64,64] bf16, 4194304 B
  int*   hist = (int*)  (ws + 113246208);        // 2048 B
  float* lsum = (float*)(ws + 113248256);        // 64 B
  float* bt1  = (float*)(ws + 113248320);        // 24576 B
  float* btp  = (float*)(ws + 113272896);        // 65536 B
  u16*   bt2h = (u16*)  (ws + 113338432);        // 1048576 B
  u16*   bt2l = (u16*)  (ws + 114387008);        // 1048576 B
  u16*   btq  = (u16*)  (ws + 115435584);        // 294912 B
  u16*   btd  = (u16*)  (ws + 115730496);        // 1048576 B
  u16*   btd2 = (u16*)  (ws + 116779072);        // 65536 B
  float* Et   = (float*)(ws + 116844608);        // 131072 B
  float* enrm = (float*)(ws + 116975680);        // 2048 B
  int*   idxb = (int*)  (ws + 116977728);        // 131072 B
  u16* g  = (u16*)(ws + 67108864);  // bf16 postvq out, overlays h2 (dead)
  u16* g2 = (u16*)ws;               // bf16 deconv1 out, overlays h1 (dead)

  hipMemsetAsync(hist, 0, 2048 + 64, stream);
  prep_enc<<<2266, 256, 0, stream>>>(ew1, ew2, pvw, emb, bt1, bt2h, bt2l, btp, Et, enrm);
  prep_dec<<<2752, 256, 0, stream>>>(qvw, dw1, dw2, btq, btd, btd2);

  conv_f32<F_CONV1><<<1024, 256, 0, stream>>>(x,  bt1, eb1, h1);
  conv2_mfma3<<<512, 256, 0, stream>>>(h1, bt2h, bt2l, eb2, h2);
  conv_f32<F_PREVQ><<<512,  256, 0, stream>>>(h2, btp, pvb, ze);

  vq_argmin_f32<<<512, 256, 0, stream>>>(ze, Et, enrm, idxb);
  vq_quant<<<128, 256, 0, stream>>>(ze, emb, idxb, qz, hist, lsum);
  finalize_kernel<<<1, 512, 0, stream>>>(hist, lsum, out, out + (out_size - 1));

  conv_mfma<M_POSTVQ> <<<512, 256, 0, stream>>>(qz, btq, qvb, g);
  conv_mfma<M_DECONV1><<<1024, 256, 0, stream>>>(g, btd, db1, g2);
  conv_mfma<M_DECONV2><<<4096, 256, 0, stream>>>(g2, btd2, db2, out + 1);
}